// Round 2
// baseline (2495.532 us; speedup 1.0000x reference)
//
#include <hip/hip_runtime.h>

typedef unsigned int u32;
typedef unsigned long long u64;
typedef _Float16 f16;
typedef __attribute__((ext_vector_type(2))) _Float16 f16x2;
typedef __attribute__((ext_vector_type(4))) _Float16 f16x4;
typedef __attribute__((ext_vector_type(8))) _Float16 f16x8;
typedef __attribute__((ext_vector_type(4))) float f32x4;
typedef __attribute__((ext_vector_type(2))) double f64x2;

// Problem constants: B=2, T=2048, D=2048, LAT=512, H=16, HD=128, NKV=4, G=4,
// SEL_DIM=64, TOPK=64, NROW = 4096

// ------------------------------------------------- transpose + cast f32->f16
// out[C][R] = (f16) in[R][C]
__global__ __launch_bounds__(256) void k_transpose_cast(const float* __restrict__ in,
                                                        f16* __restrict__ out, int R, int C)
{
  __shared__ float tile[32][33];
  int c0 = blockIdx.x * 32, r0 = blockIdx.y * 32;
  int tx = threadIdx.x & 31, ty = threadIdx.x >> 5;  // ty 0..7
  #pragma unroll
  for (int i = ty; i < 32; i += 8) tile[i][tx] = in[(size_t)(r0 + i) * C + c0 + tx];
  __syncthreads();
  #pragma unroll
  for (int i = ty; i < 32; i += 8) out[(size_t)(c0 + i) * R + r0 + tx] = (f16)tile[tx][i];
}

// ------------------------------------------------------------- cast f32->f16
__global__ __launch_bounds__(256) void k_cast_f16(const float* __restrict__ in,
                                                  f16* __restrict__ out, int n4)
{
  int i = blockIdx.x * 256 + threadIdx.x;
  if (i >= n4) return;
  f32x4 v = *(const f32x4*)&in[(size_t)i * 4];
  f16x4 h; h.x = (f16)v.x; h.y = (f16)v.y; h.z = (f16)v.z; h.w = (f16)v.w;
  *(f16x4*)&out[(size_t)i * 4] = h;
}

// ------------------------------------------------------------- fp64 selector weights
// Bsel [2048][128]: cols 0..63 = Wq[:, :64] ; cols 64..127 = (Wkd @ Wku[:, :64]) in fp64
__global__ void k_prep_sel(const float* __restrict__ Wq, const float* __restrict__ Wkd,
                           const float* __restrict__ Wku, double* __restrict__ Bsel)
{
  const int k = blockIdx.x;   // 0..2047
  const int j = threadIdx.x;  // 0..63
  Bsel[(size_t)k * 128 + j] = (double)Wq[(size_t)k * 2048 + j];
  double s = 0.0;
  for (int l = 0; l < 512; ++l)
    s = fma((double)Wkd[(size_t)k * 512 + l], (double)Wku[(size_t)l * 1024 + j], s);
  Bsel[(size_t)k * 128 + 64 + j] = s;
}

__global__ void k_bias_sel(const float* __restrict__ bq, const float* __restrict__ bkd,
                           const float* __restrict__ Wku, const float* __restrict__ bku,
                           double* __restrict__ bsel)
{
  int j = threadIdx.x;  // 0..127
  if (j < 64) {
    bsel[j] = (double)bq[j];
  } else {
    int jj = j - 64;
    double s = (double)bku[jj];
    for (int l = 0; l < 512; ++l)
      s = fma((double)bkd[l], (double)Wku[(size_t)l * 1024 + jj], s);
    bsel[j] = s;
  }
}

// ------------------------------------------------------------- fp64 selector GEMM
// qs64/ks64 = x[4096][2048] @ Bsel[2048][128] + bsel.  Products of fp32 inputs are
// exact in fp64 -> ordering matches an fp64 numpy reference to ~1e-14.
// BM=32, BN=64, BK=32; 256 thr (16x16, microtile 2x4); reg-staged double buffer.
__global__ __launch_bounds__(256) void k_gemm_sel_f64(const float* __restrict__ A,
                                                      const double* __restrict__ Bsel,
                                                      const double* __restrict__ bias,
                                                      double* __restrict__ qs64,
                                                      double* __restrict__ ks64)
{
  __shared__ double As[32][33];
  __shared__ double Bs[32][66];
  const int m0 = blockIdx.x * 32, n0 = blockIdx.y * 64;
  const int tid = threadIdx.x;
  const int tx = tid & 15, ty = tid >> 4;
  const int ar = tid >> 3, ac4 = (tid & 7) * 4;  // A staging: row, col
  double acc[2][4] = {};

  f32x4 aN = *(const f32x4*)&A[(size_t)(m0 + ar) * 2048 + ac4];
  f64x2 bN[4];
  #pragma unroll
  for (int it = 0; it < 4; ++it) {
    int c = it * 256 + tid; int kk = c >> 5, n2 = (c & 31) * 2;
    bN[it] = *(const f64x2*)&Bsel[(size_t)kk * 128 + n0 + n2];
  }
  for (int k0 = 0; k0 < 2048; k0 += 32) {
    __syncthreads();
    As[ar][ac4] = (double)aN.x; As[ar][ac4 + 1] = (double)aN.y;
    As[ar][ac4 + 2] = (double)aN.z; As[ar][ac4 + 3] = (double)aN.w;
    #pragma unroll
    for (int it = 0; it < 4; ++it) {
      int c = it * 256 + tid; int kk = c >> 5, n2 = (c & 31) * 2;
      Bs[kk][n2] = bN[it].x; Bs[kk][n2 + 1] = bN[it].y;
    }
    __syncthreads();
    if (k0 + 32 < 2048) {  // prefetch next tile (hides HBM/L2 latency under fp64 FMA)
      aN = *(const f32x4*)&A[(size_t)(m0 + ar) * 2048 + k0 + 32 + ac4];
      #pragma unroll
      for (int it = 0; it < 4; ++it) {
        int c = it * 256 + tid; int kk = c >> 5, n2 = (c & 31) * 2;
        bN[it] = *(const f64x2*)&Bsel[(size_t)(k0 + 32 + kk) * 128 + n0 + n2];
      }
    }
    #pragma unroll
    for (int kk = 0; kk < 32; ++kk) {
      double a0 = As[ty * 2][kk], a1 = As[ty * 2 + 1][kk];   // LDS broadcast
      f64x2 b01 = *(const f64x2*)&Bs[kk][tx * 4];
      f64x2 b23 = *(const f64x2*)&Bs[kk][tx * 4 + 2];
      acc[0][0] = fma(a0, b01.x, acc[0][0]); acc[0][1] = fma(a0, b01.y, acc[0][1]);
      acc[0][2] = fma(a0, b23.x, acc[0][2]); acc[0][3] = fma(a0, b23.y, acc[0][3]);
      acc[1][0] = fma(a1, b01.x, acc[1][0]); acc[1][1] = fma(a1, b01.y, acc[1][1]);
      acc[1][2] = fma(a1, b23.x, acc[1][2]); acc[1][3] = fma(a1, b23.y, acc[1][3]);
    }
  }
  #pragma unroll
  for (int i = 0; i < 2; ++i) {
    int row = m0 + ty * 2 + i;
    #pragma unroll
    for (int j = 0; j < 4; ++j) {
      int n = n0 + tx * 4 + j;
      double v = acc[i][j] + bias[n];
      if (n < 64) qs64[(size_t)row * 64 + n] = v;
      else        ks64[(size_t)row * 64 + (n - 64)] = v;
    }
  }
}

// ------------------------------------------------------------- fp16 MFMA GEMM (m97 structure)
// C[M][N] = A[M][K] @ BT[N][K]^T + bias.  128x128 tile, BK=64, 4 waves, global_load_lds(16B).
template <bool OUTF16>
__global__ __launch_bounds__(256) void k_gemm_bt(const f16* __restrict__ A,
                                                 const f16* __restrict__ BT,
                                                 const float* __restrict__ bias,
                                                 float* __restrict__ C, f16* __restrict__ Ch,
                                                 int M, int N, int K, int lda, int ldb, int ldc)
{
  __shared__ __align__(16) f16 As[128 * 64];
  __shared__ __align__(16) f16 Bs[128 * 64];
  const int tid = threadIdx.x;
  const int lane = tid & 63;
  const int wave = tid >> 6;
  const int m0 = blockIdx.x * 128, n0 = blockIdx.y * 128;
  const int wr = (wave >> 1) * 64, wc = (wave & 1) * 64;
  const int lrow = lane & 15;
  const int kgrp = (lane >> 4) * 8;
  f32x4 acc[4][4] = {};

  for (int k0 = 0; k0 < K; k0 += 64) {
    __syncthreads();
    #pragma unroll
    for (int it = 0; it < 4; ++it) {
      int c = it * 256 + tid;
      int r = c >> 3, c8 = (c & 7) * 8;
      int lbase = (it * 256 + (tid & 192)) * 8;  // wave-uniform LDS offset
      const f16* ga = A + (size_t)(m0 + r) * lda + k0 + c8;
      __builtin_amdgcn_global_load_lds((const __attribute__((address_space(1))) u32*)ga,
                                       (__attribute__((address_space(3))) u32*)&As[lbase],
                                       16, 0, 0);
      const f16* gb = BT + (size_t)(n0 + r) * ldb + k0 + c8;
      __builtin_amdgcn_global_load_lds((const __attribute__((address_space(1))) u32*)gb,
                                       (__attribute__((address_space(3))) u32*)&Bs[lbase],
                                       16, 0, 0);
    }
    __syncthreads();
    #pragma unroll
    for (int ks = 0; ks < 2; ++ks) {
      f16x8 af[4], bfr[4];
      #pragma unroll
      for (int m = 0; m < 4; ++m)
        af[m] = *(const f16x8*)&As[(wr + m * 16 + lrow) * 64 + ks * 32 + kgrp];
      #pragma unroll
      for (int n = 0; n < 4; ++n)
        bfr[n] = *(const f16x8*)&Bs[(wc + n * 16 + lrow) * 64 + ks * 32 + kgrp];
      #pragma unroll
      for (int m = 0; m < 4; ++m)
        #pragma unroll
        for (int n = 0; n < 4; ++n)
          acc[m][n] = __builtin_amdgcn_mfma_f32_16x16x32_f16(af[m], bfr[n], acc[m][n], 0, 0, 0);
    }
  }
  const int rbase = m0 + wr + (lane >> 4) * 4;  // C/D: col=lane&15, row=(lane>>4)*4+reg [m89]
  #pragma unroll
  for (int n = 0; n < 4; ++n) {
    int col = n0 + wc + n * 16 + lrow;
    float bv = bias ? bias[col] : 0.0f;
    #pragma unroll
    for (int m = 0; m < 4; ++m) {
      #pragma unroll
      for (int j = 0; j < 4; ++j) {
        int rowi = rbase + m * 16 + j;
        float v = acc[m][n][j] + bv;
        if (OUTF16) Ch[(size_t)rowi * ldc + col] = (f16)v;
        else        C[(size_t)rowi * ldc + col] = v;
      }
    }
  }
}

// ------------------------------------------------------------- RoPE tables
// pair i uses freq index (2i) mod 64 (concat([freqs,freqs])[::2] quirk of the reference)
__global__ void k_rope_table(float* __restrict__ rc, float* __restrict__ rs)
{
  int t = blockIdx.x, i = threadIdx.x;  // 2048 x 64
  int fi = (2 * i) & 63;
  double inv = pow(10000.0, -(double)fi / 64.0);
  double a = (double)t * inv;
  rc[t * 64 + i] = (float)cos(a);
  rs[t * 64 + i] = (float)sin(a);
}

__global__ __launch_bounds__(256) void k_rope_q(const f16* __restrict__ q,
                                                const float* __restrict__ rc,
                                                const float* __restrict__ rs,
                                                f16* __restrict__ out)
{
  int g = blockIdx.x * 256 + threadIdx.x;  // 4096*16*64
  int row = g >> 10, rem = g & 1023;
  int h = rem >> 6, i = rem & 63;
  int t = row & 2047;
  size_t base = (size_t)row * 2048 + h * 128 + 2 * i;
  f16x2 v = *(const f16x2*)&q[base];
  float x1 = (float)v.x, x2 = (float)v.y;
  float c = rc[t * 64 + i], s = rs[t * 64 + i];
  f16x2 o; o.x = (f16)(x1 * c - x2 * s); o.y = (f16)(x1 * s + x2 * c);
  *(f16x2*)&out[base] = o;
}

__global__ __launch_bounds__(256) void k_rope_kv(const f16* __restrict__ kv,
                                                 const float* __restrict__ rc,
                                                 const float* __restrict__ rs,
                                                 f16* __restrict__ kout, f16* __restrict__ vout)
{
  int g = blockIdx.x * 256 + threadIdx.x;  // 4096*4*64
  int row = g >> 8, rem = g & 255;
  int kvh = rem >> 6, i = rem & 63;
  int t = row & 2047;
  size_t kb = (size_t)row * 1024 + kvh * 128 + 2 * i;
  f16x2 kvp = *(const f16x2*)&kv[kb];
  float x1 = (float)kvp.x, x2 = (float)kvp.y;
  float c = rc[t * 64 + i], s = rs[t * 64 + i];
  size_t ob = (size_t)row * 512 + kvh * 128 + 2 * i;
  f16x2 ko; ko.x = (f16)(x1 * c - x2 * s); ko.y = (f16)(x1 * s + x2 * c);
  *(f16x2*)&kout[ob] = ko;
  f16x2 vp = *(const f16x2*)&kv[(size_t)row * 1024 + 512 + kvh * 128 + 2 * i];
  *(f16x2*)&vout[ob] = vp;
}

// ------------------------------------------------------------- exact top-64, fp64 scores
// 2 rows/block (shares ks64 reads). Radix-select over order-preserving u64 keys;
// ties broken by lowest index (matches top_k); diagonal forced.
__global__ __launch_bounds__(256) void k_topk64(const double* __restrict__ qs,
                                                const double* __restrict__ ks,
                                                int* __restrict__ selcnt,
                                                int* __restrict__ selidx)
{
  const int r0 = blockIdx.x * 2;
  const int b = r0 >> 11;
  const int t0 = r0 & 2047, t1 = t0 + 1;
  const int tid = threadIdx.x;
  __shared__ double qrow[2][64];
  __shared__ u64 su[2][2048];
  __shared__ unsigned hist[256];
  __shared__ u64 s_bsel;
  __shared__ unsigned s_larger;
  __shared__ int s_cnt;

  if (tid < 128) qrow[tid >> 6][tid & 63] = qs[(size_t)(r0 + (tid >> 6)) * 64 + (tid & 63)];
  __syncthreads();
  const bool triv0 = (t0 < 64), triv1 = (t1 < 64);
  if (!(triv0 && triv1)) {
    for (int jj = tid; jj <= t1; jj += 256) {
      const double* kp = &ks[((size_t)(b * 2048 + jj)) * 64];
      double sc0 = 0.0, sc1 = 0.0;
      #pragma unroll
      for (int d2 = 0; d2 < 32; ++d2) {
        f64x2 kd = *(const f64x2*)&kp[d2 * 2];
        sc0 = fma(qrow[0][d2 * 2], kd.x, sc0); sc0 = fma(qrow[0][d2 * 2 + 1], kd.y, sc0);
        sc1 = fma(qrow[1][d2 * 2], kd.x, sc1); sc1 = fma(qrow[1][d2 * 2 + 1], kd.y, sc1);
      }
      if (!triv0 && jj <= t0) {
        u64 u = (u64)__double_as_longlong(sc0);
        su[0][jj] = (u >> 63) ? ~u : (u | 0x8000000000000000ull);
      }
      if (!triv1) {
        u64 u = (u64)__double_as_longlong(sc1);
        su[1][jj] = (u >> 63) ? ~u : (u | 0x8000000000000000ull);
      }
    }
    __syncthreads();
  }
  for (int lr = 0; lr < 2; ++lr) {
    const int t = t0 + lr;
    int* outp = selidx + (size_t)(r0 + lr) * 68;
    if (t < 64) {  // all causal positions selected (block-uniform branch)
      for (int jj = tid; jj <= t; jj += 256) outp[jj] = jj;
      if (tid == 0) selcnt[r0 + lr] = t + 1;
      continue;
    }
    const u64* S = su[lr];
    u64 prefix = 0;
    int remaining = 64;
    for (int byte = 7; byte >= 0; --byte) {
      const int sh = byte * 8;
      hist[tid] = 0;
      __syncthreads();
      for (int jj = tid; jj <= t; jj += 256) {
        u64 u = S[jj];
        bool ok = (byte == 7) || (((u ^ prefix) >> (sh + 8)) == 0);
        if (ok) atomicAdd(&hist[(unsigned)((u >> sh) & 255)], 1u);
      }
      __syncthreads();
      if (tid == 0) {
        unsigned cum = 0; int v = 255;
        for (;; --v) {
          unsigned h = hist[v];
          if (cum + h >= (unsigned)remaining || v == 0) break;
          cum += h;
        }
        s_bsel = (u64)(unsigned)v; s_larger = cum;
      }
      __syncthreads();
      prefix |= (s_bsel << sh);
      remaining -= (int)s_larger;
      __syncthreads();
    }
    if (tid == 0) { s_cnt = 1; outp[0] = t; }  // diagonal first, always
    __syncthreads();
    for (int jj = tid; jj <= t; jj += 256) {
      if (jj != t && S[jj] > prefix) {
        int p = atomicAdd(&s_cnt, 1);
        outp[p] = jj;
      }
    }
    __syncthreads();
    if (tid == 0) {
      int cnt = s_cnt, taken = 0;
      for (int jj = 0; jj <= t && taken < remaining; ++jj) {
        if (S[jj] == prefix) {
          ++taken;
          if (jj != t) outp[cnt++] = jj;
        }
      }
      selcnt[r0 + lr] = cnt;  // 64 or 65
    }
    __syncthreads();
  }
}

// ------------------------------------------------------------- sparse attention
// Block per (row, kvh); wave w handles q-head kvh*4+w. K/V gathered from L2-resident buffers.
__global__ __launch_bounds__(256) void k_attn(const f16* __restrict__ qr,
                                              const f16* __restrict__ kr,
                                              const f16* __restrict__ vv,
                                              const int* __restrict__ selcnt,
                                              const int* __restrict__ selidx,
                                              f16* __restrict__ y)
{
  const int blk = blockIdx.x;  // row*4 + kvh
  const int row = blk >> 2, kvh = blk & 3;
  const int b = row >> 11;
  const int tid = threadIdx.x, lane = tid & 63, wave = tid >> 6;
  const int cnt = selcnt[row];
  __shared__ int sidx[68];
  __shared__ f16 qlds[4][128];
  __shared__ float pl[4][66];
  if (tid < cnt) sidx[tid] = selidx[(size_t)row * 68 + tid];
  *(f16x2*)&qlds[wave][lane * 2] =
      *(const f16x2*)&qr[((size_t)row * 16 + kvh * 4 + wave) * 128 + lane * 2];
  __syncthreads();

  const float SCALE = 0.08838834764831845f;  // 1/sqrt(128)
  auto dotk = [&](int key) -> float {
    const f16* kp = &kr[((size_t)(b * 2048 + key)) * 512 + kvh * 128];
    float s = 0.0f;
    #pragma unroll
    for (int i = 0; i < 16; ++i) {
      f16x8 k8 = *(const f16x8*)&kp[i * 8];
      f16x8 q8 = *(const f16x8*)&qlds[wave][i * 8];
      #pragma unroll
      for (int e = 0; e < 8; ++e) s = fmaf((float)q8[e], (float)k8[e], s);
    }
    return s * SCALE;
  };

  float s1 = -__builtin_inff(), s2 = -__builtin_inff();
  if (lane < cnt) s1 = dotk(sidx[lane]);
  if (lane + 64 < cnt) s2 = dotk(sidx[lane + 64]);  // only lane 0, cnt==65
  float mx = fmaxf(s1, s2);
  #pragma unroll
  for (int off = 32; off; off >>= 1) mx = fmaxf(mx, __shfl_xor(mx, off));
  float p1 = (lane < cnt) ? __expf(s1 - mx) : 0.0f;
  float p2 = (lane + 64 < cnt) ? __expf(s2 - mx) : 0.0f;
  float l = p1 + p2;
  #pragma unroll
  for (int off = 32; off; off >>= 1) l += __shfl_xor(l, off);
  float linv = 1.0f / l;
  pl[wave][lane] = p1;
  if (lane == 0) pl[wave][64] = p2;
  __syncthreads();

  float y0 = 0.0f, y1 = 0.0f;
  const int d2 = lane * 2;
  for (int j = 0; j < cnt; ++j) {
    float p = pl[wave][j];
    int key = sidx[j];
    f16x2 v2 = *(const f16x2*)&vv[((size_t)(b * 2048 + key)) * 512 + kvh * 128 + d2];
    y0 = fmaf(p, (float)v2.x, y0);
    y1 = fmaf(p, (float)v2.y, y1);
  }
  y0 *= linv; y1 *= linv;
  f16x2 o; o.x = (f16)y0; o.y = (f16)y1;
  *(f16x2*)&y[(size_t)row * 2048 + (kvh * 4 + wave) * 128 + d2] = o;
}

// ================================================================ launch
extern "C" void kernel_launch(void* const* d_in, const int* in_sizes, int n_in,
                              void* d_out, int out_size, void* d_ws, size_t ws_size,
                              hipStream_t stream)
{
  (void)in_sizes; (void)n_in; (void)out_size; (void)ws_size;
  const float* x   = (const float*)d_in[0];
  const float* Wq  = (const float*)d_in[1];
  const float* bq  = (const float*)d_in[2];
  const float* Wkd = (const float*)d_in[3];
  const float* bkd = (const float*)d_in[4];
  const float* Wku = (const float*)d_in[5];
  const float* bku = (const float*)d_in[6];
  const float* Wo  = (const float*)d_in[7];
  const float* bo  = (const float*)d_in[8];
  float* out = (float*)d_out;

  char* ws = (char*)d_ws;
  size_t o = 0;
  auto alloc = [&](size_t bytes) -> void* {
    o = (o + 255) & ~(size_t)255;
    void* p = ws + o;
    o += bytes;
    return p;
  };
  f16* WqT   = (f16*)alloc(2048ull * 2048 * 2);
  f16* WoT   = (f16*)alloc(2048ull * 2048 * 2);
  f16* WkdT  = (f16*)alloc(512ull * 2048 * 2);
  f16* WkuT  = (f16*)alloc(1024ull * 512 * 2);
  f16* xh    = (f16*)alloc(4096ull * 2048 * 2);
  f16* qmain = (f16*)alloc(4096ull * 2048 * 2);  // reused as y after rope
  f16* kvh_  = (f16*)alloc(4096ull * 1024 * 2);
  f16* cbf   = (f16*)alloc(4096ull * 512 * 2);
  float* rc  = (float*)alloc(2048ull * 64 * 4);
  float* rs  = (float*)alloc(2048ull * 64 * 4);
  f16* qrope = (f16*)alloc(4096ull * 2048 * 2);
  f16* krope = (f16*)alloc(4096ull * 512 * 2);
  f16* vbf   = (f16*)alloc(4096ull * 512 * 2);
  int* selcnt = (int*)alloc(4096ull * 4);
  int* selidx = (int*)alloc(4096ull * 68 * 4);
  double* Bsel = (double*)alloc(2048ull * 128 * 8);
  double* bsel = (double*)alloc(128 * 8);
  double* qs64 = (double*)alloc(4096ull * 64 * 8);
  double* ks64 = (double*)alloc(4096ull * 64 * 8);
  f16* yh = qmain;  // alias: qmain dead after k_rope_q

  // --- weight prep ---
  k_transpose_cast<<<dim3(64, 64), 256, 0, stream>>>(Wq, WqT, 2048, 2048);
  k_transpose_cast<<<dim3(16, 64), 256, 0, stream>>>(Wkd, WkdT, 2048, 512);
  k_transpose_cast<<<dim3(32, 16), 256, 0, stream>>>(Wku, WkuT, 512, 1024);
  k_transpose_cast<<<dim3(64, 64), 256, 0, stream>>>(Wo, WoT, 2048, 2048);
  k_cast_f16<<<8192, 256, 0, stream>>>(x, xh, 2097152);

  // --- fp64 selector path ---
  k_prep_sel<<<2048, 64, 0, stream>>>(Wq, Wkd, Wku, Bsel);
  k_bias_sel<<<1, 128, 0, stream>>>(bq, bkd, Wku, bku, bsel);
  k_gemm_sel_f64<<<dim3(128, 2), 256, 0, stream>>>(x, Bsel, bsel, qs64, ks64);

  // --- fp16 MFMA main path ---
  k_gemm_bt<true><<<dim3(32, 16), 256, 0, stream>>>(xh, WqT, bq, nullptr, qmain,
                                                    4096, 2048, 2048, 2048, 2048, 2048);
  k_gemm_bt<true><<<dim3(32, 4), 256, 0, stream>>>(xh, WkdT, bkd, nullptr, cbf,
                                                   4096, 512, 2048, 2048, 2048, 512);
  k_gemm_bt<true><<<dim3(32, 8), 256, 0, stream>>>(cbf, WkuT, bku, nullptr, kvh_,
                                                   4096, 1024, 512, 512, 512, 1024);

  // --- RoPE ---
  k_rope_table<<<2048, 64, 0, stream>>>(rc, rs);
  k_rope_q<<<16384, 256, 0, stream>>>(qmain, rc, rs, qrope);
  k_rope_kv<<<4096, 256, 0, stream>>>(kvh_, rc, rs, krope, vbf);

  // --- selector top-k (fp64 exact) ---
  k_topk64<<<2048, 256, 0, stream>>>(qs64, ks64, selcnt, selidx);

  // --- sparse attention ---
  k_attn<<<16384, 256, 0, stream>>>(qrope, krope, vbf, selcnt, selidx, yh);

  // --- output projection ---
  k_gemm_bt<false><<<dim3(32, 16), 256, 0, stream>>>(yh, WoT, bo, out, nullptr,
                                                     4096, 2048, 2048, 2048, 2048, 2048);
}

// Round 4
// 845.031 us; speedup vs baseline: 2.9532x; 2.9532x over previous
//
#include <hip/hip_runtime.h>

typedef unsigned int u32;
typedef unsigned long long u64;
typedef _Float16 f16;
typedef __attribute__((ext_vector_type(2))) _Float16 f16x2;
typedef __attribute__((ext_vector_type(4))) _Float16 f16x4;
typedef __attribute__((ext_vector_type(8))) _Float16 f16x8;
typedef __attribute__((ext_vector_type(4))) float f32x4;
typedef __attribute__((ext_vector_type(2))) double f64x2;

// Problem constants: B=2, T=2048, D=2048, LAT=512, H=16, HD=128, NKV=4, G=4,
// SEL_DIM=64, TOPK=64, NROW = 4096

// ------------------------------------------------- transpose + cast f32->f16
// out[C][R] = (f16) in[R][C]
__global__ __launch_bounds__(256) void k_transpose_cast(const float* __restrict__ in,
                                                        f16* __restrict__ out, int R, int C)
{
  __shared__ float tile[32][33];
  int c0 = blockIdx.x * 32, r0 = blockIdx.y * 32;
  int tx = threadIdx.x & 31, ty = threadIdx.x >> 5;  // ty 0..7
  #pragma unroll
  for (int i = ty; i < 32; i += 8) tile[i][tx] = in[(size_t)(r0 + i) * C + c0 + tx];
  __syncthreads();
  #pragma unroll
  for (int i = ty; i < 32; i += 8) out[(size_t)(c0 + i) * R + r0 + tx] = (f16)tile[tx][i];
}

// ------------------------------------------------------------- cast f32->f16
__global__ __launch_bounds__(256) void k_cast_f16(const float* __restrict__ in,
                                                  f16* __restrict__ out, int n4)
{
  int i = blockIdx.x * 256 + threadIdx.x;
  if (i >= n4) return;
  f32x4 v = *(const f32x4*)&in[(size_t)i * 4];
  f16x4 h; h.x = (f16)v.x; h.y = (f16)v.y; h.z = (f16)v.z; h.w = (f16)v.w;
  *(f16x4*)&out[(size_t)i * 4] = h;
}

// ------------------------------------------------------------- fp64 selector weights
// Bsel [2048][128]: cols 0..63 = Wq[:, :64] ; cols 64..127 = (Wkd @ Wku[:, :64]) in fp64
__global__ void k_prep_sel(const float* __restrict__ Wq, const float* __restrict__ Wkd,
                           const float* __restrict__ Wku, double* __restrict__ Bsel)
{
  const int k = blockIdx.x;   // 0..2047
  const int j = threadIdx.x;  // 0..63
  Bsel[(size_t)k * 128 + j] = (double)Wq[(size_t)k * 2048 + j];
  double s = 0.0;
  for (int l = 0; l < 512; ++l)
    s = fma((double)Wkd[(size_t)k * 512 + l], (double)Wku[(size_t)l * 1024 + j], s);
  Bsel[(size_t)k * 128 + 64 + j] = s;
}

__global__ void k_bias_sel(const float* __restrict__ bq, const float* __restrict__ bkd,
                           const float* __restrict__ Wku, const float* __restrict__ bku,
                           double* __restrict__ bsel)
{
  int j = threadIdx.x;  // 0..127
  if (j < 64) {
    bsel[j] = (double)bq[j];
  } else {
    int jj = j - 64;
    double s = (double)bku[jj];
    for (int l = 0; l < 512; ++l)
      s = fma((double)bkd[l], (double)Wku[(size_t)l * 1024 + jj], s);
    bsel[j] = s;
  }
}

// ------------------------------------------------------------- fp64 selector GEMM
// qs64/ks64 = x[4096][2048] @ Bsel[2048][128] + bsel.
__global__ __launch_bounds__(256) void k_gemm_sel_f64(const float* __restrict__ A,
                                                      const double* __restrict__ Bsel,
                                                      const double* __restrict__ bias,
                                                      double* __restrict__ qs64,
                                                      double* __restrict__ ks64)
{
  __shared__ double As[32][33];
  __shared__ double Bs[32][66];
  const int m0 = blockIdx.x * 32, n0 = blockIdx.y * 64;
  const int tid = threadIdx.x;
  const int tx = tid & 15, ty = tid >> 4;
  const int ar = tid >> 3, ac4 = (tid & 7) * 4;
  double acc[2][4] = {};

  f32x4 aN = *(const f32x4*)&A[(size_t)(m0 + ar) * 2048 + ac4];
  f64x2 bN[4];
  #pragma unroll
  for (int it = 0; it < 4; ++it) {
    int c = it * 256 + tid; int kk = c >> 5, n2 = (c & 31) * 2;
    bN[it] = *(const f64x2*)&Bsel[(size_t)kk * 128 + n0 + n2];
  }
  for (int k0 = 0; k0 < 2048; k0 += 32) {
    __syncthreads();
    As[ar][ac4] = (double)aN.x; As[ar][ac4 + 1] = (double)aN.y;
    As[ar][ac4 + 2] = (double)aN.z; As[ar][ac4 + 3] = (double)aN.w;
    #pragma unroll
    for (int it = 0; it < 4; ++it) {
      int c = it * 256 + tid; int kk = c >> 5, n2 = (c & 31) * 2;
      Bs[kk][n2] = bN[it].x; Bs[kk][n2 + 1] = bN[it].y;
    }
    __syncthreads();
    if (k0 + 32 < 2048) {
      aN = *(const f32x4*)&A[(size_t)(m0 + ar) * 2048 + k0 + 32 + ac4];
      #pragma unroll
      for (int it = 0; it < 4; ++it) {
        int c = it * 256 + tid; int kk = c >> 5, n2 = (c & 31) * 2;
        bN[it] = *(const f64x2*)&Bsel[(size_t)(k0 + 32 + kk) * 128 + n0 + n2];
      }
    }
    #pragma unroll
    for (int kk = 0; kk < 32; ++kk) {
      double a0 = As[ty * 2][kk], a1 = As[ty * 2 + 1][kk];
      f64x2 b01 = *(const f64x2*)&Bs[kk][tx * 4];
      f64x2 b23 = *(const f64x2*)&Bs[kk][tx * 4 + 2];
      acc[0][0] = fma(a0, b01.x, acc[0][0]); acc[0][1] = fma(a0, b01.y, acc[0][1]);
      acc[0][2] = fma(a0, b23.x, acc[0][2]); acc[0][3] = fma(a0, b23.y, acc[0][3]);
      acc[1][0] = fma(a1, b01.x, acc[1][0]); acc[1][1] = fma(a1, b01.y, acc[1][1]);
      acc[1][2] = fma(a1, b23.x, acc[1][2]); acc[1][3] = fma(a1, b23.y, acc[1][3]);
    }
  }
  #pragma unroll
  for (int i = 0; i < 2; ++i) {
    int row = m0 + ty * 2 + i;
    #pragma unroll
    for (int j = 0; j < 4; ++j) {
      int n = n0 + tx * 4 + j;
      double v = acc[i][j] + bias[n];
      if (n < 64) qs64[(size_t)row * 64 + n] = v;
      else        ks64[(size_t)row * 64 + (n - 64)] = v;
    }
  }
}

// ------------------------------------------------------------- fp16 MFMA GEMM (m97 structure)
// C[M][N] = A[M][K] @ BT[N][K]^T + bias.  128x128 tile, BK=64, 4 waves, global_load_lds(16B).
template <bool OUTF16>
__global__ __launch_bounds__(256) void k_gemm_bt(const f16* __restrict__ A,
                                                 const f16* __restrict__ BT,
                                                 const float* __restrict__ bias,
                                                 float* __restrict__ C, f16* __restrict__ Ch,
                                                 int M, int N, int K, int lda, int ldb, int ldc)
{
  __shared__ __align__(16) f16 As[128 * 64];
  __shared__ __align__(16) f16 Bs[128 * 64];
  const int tid = threadIdx.x;
  const int lane = tid & 63;
  const int wave = tid >> 6;
  const int m0 = blockIdx.x * 128, n0 = blockIdx.y * 128;
  const int wr = (wave >> 1) * 64, wc = (wave & 1) * 64;
  const int lrow = lane & 15;
  const int kgrp = (lane >> 4) * 8;
  f32x4 acc[4][4] = {};

  for (int k0 = 0; k0 < K; k0 += 64) {
    __syncthreads();
    #pragma unroll
    for (int it = 0; it < 4; ++it) {
      int c = it * 256 + tid;
      int r = c >> 3, c8 = (c & 7) * 8;
      int lbase = (it * 256 + (tid & 192)) * 8;  // wave-uniform LDS offset
      const f16* ga = A + (size_t)(m0 + r) * lda + k0 + c8;
      __builtin_amdgcn_global_load_lds((const __attribute__((address_space(1))) u32*)ga,
                                       (__attribute__((address_space(3))) u32*)&As[lbase],
                                       16, 0, 0);
      const f16* gb = BT + (size_t)(n0 + r) * ldb + k0 + c8;
      __builtin_amdgcn_global_load_lds((const __attribute__((address_space(1))) u32*)gb,
                                       (__attribute__((address_space(3))) u32*)&Bs[lbase],
                                       16, 0, 0);
    }
    __syncthreads();
    #pragma unroll
    for (int ks = 0; ks < 2; ++ks) {
      f16x8 af[4], bfr[4];
      #pragma unroll
      for (int m = 0; m < 4; ++m)
        af[m] = *(const f16x8*)&As[(wr + m * 16 + lrow) * 64 + ks * 32 + kgrp];
      #pragma unroll
      for (int n = 0; n < 4; ++n)
        bfr[n] = *(const f16x8*)&Bs[(wc + n * 16 + lrow) * 64 + ks * 32 + kgrp];
      #pragma unroll
      for (int m = 0; m < 4; ++m)
        #pragma unroll
        for (int n = 0; n < 4; ++n)
          acc[m][n] = __builtin_amdgcn_mfma_f32_16x16x32_f16(af[m], bfr[n], acc[m][n], 0, 0, 0);
    }
  }
  const int rbase = m0 + wr + (lane >> 4) * 4;  // C/D: col=lane&15, row=(lane>>4)*4+reg [m89]
  #pragma unroll
  for (int n = 0; n < 4; ++n) {
    int col = n0 + wc + n * 16 + lrow;
    float bv = bias ? bias[col] : 0.0f;
    #pragma unroll
    for (int m = 0; m < 4; ++m) {
      #pragma unroll
      for (int j = 0; j < 4; ++j) {
        int rowi = rbase + m * 16 + j;
        float v = acc[m][n][j] + bv;
        if (OUTF16) Ch[(size_t)rowi * ldc + col] = (f16)v;
        else        C[(size_t)rowi * ldc + col] = v;
      }
    }
  }
}

// ------------------------------------------------------------- RoPE tables
__global__ void k_rope_table(float* __restrict__ rc, float* __restrict__ rs)
{
  int t = blockIdx.x, i = threadIdx.x;  // 2048 x 64
  int fi = (2 * i) & 63;
  double inv = pow(10000.0, -(double)fi / 64.0);
  double a = (double)t * inv;
  rc[t * 64 + i] = (float)cos(a);
  rs[t * 64 + i] = (float)sin(a);
}

__global__ __launch_bounds__(256) void k_rope_q(const f16* __restrict__ q,
                                                const float* __restrict__ rc,
                                                const float* __restrict__ rs,
                                                f16* __restrict__ out)
{
  int g = blockIdx.x * 256 + threadIdx.x;  // 4096*16*64
  int row = g >> 10, rem = g & 1023;
  int h = rem >> 6, i = rem & 63;
  int t = row & 2047;
  size_t base = (size_t)row * 2048 + h * 128 + 2 * i;
  f16x2 v = *(const f16x2*)&q[base];
  float x1 = (float)v.x, x2 = (float)v.y;
  float c = rc[t * 64 + i], s = rs[t * 64 + i];
  f16x2 o; o.x = (f16)(x1 * c - x2 * s); o.y = (f16)(x1 * s + x2 * c);
  *(f16x2*)&out[base] = o;
}

__global__ __launch_bounds__(256) void k_rope_kv(const f16* __restrict__ kv,
                                                 const float* __restrict__ rc,
                                                 const float* __restrict__ rs,
                                                 f16* __restrict__ kout, f16* __restrict__ vout)
{
  int g = blockIdx.x * 256 + threadIdx.x;  // 4096*4*64
  int row = g >> 8, rem = g & 255;
  int kvh = rem >> 6, i = rem & 63;
  int t = row & 2047;
  size_t kb = (size_t)row * 1024 + kvh * 128 + 2 * i;
  f16x2 kvp = *(const f16x2*)&kv[kb];
  float x1 = (float)kvp.x, x2 = (float)kvp.y;
  float c = rc[t * 64 + i], s = rs[t * 64 + i];
  size_t ob = (size_t)row * 512 + kvh * 128 + 2 * i;
  f16x2 ko; ko.x = (f16)(x1 * c - x2 * s); ko.y = (f16)(x1 * s + x2 * c);
  *(f16x2*)&kout[ob] = ko;
  f16x2 vp = *(const f16x2*)&kv[(size_t)row * 1024 + 512 + kvh * 128 + 2 * i];
  *(f16x2*)&vout[ob] = vp;
}

// ------------------------------------------------------------- exact top-64, fp64 scores
// FULLY DETERMINISTIC parallel select (R3's shfl-scan + atomic-scatter emit showed
// replay nondeterminism; this version uses only barrier-stepped shared-memory scans
// and position-computed writes — bit-identical output every run).
// Semantics proven equal to R2's serial version: top-64 by score, ties lowest-index
// first, diagonal forced to slot 0. Emitted order: diag, greaters asc, ties asc.
__global__ __launch_bounds__(256) void k_topk64(const double* __restrict__ qs,
                                                const double* __restrict__ ks,
                                                int* __restrict__ selcnt,
                                                int* __restrict__ selidx)
{
  const int row = blockIdx.x;
  const int b = row >> 11, t = row & 2047;
  const int tid = threadIdx.x;
  int* outp = selidx + (size_t)row * 68;
  if (t < 64) {  // all causal positions selected
    for (int jj = tid; jj <= t; jj += 256) outp[jj] = jj;
    if (tid == 0) selcnt[row] = t + 1;
    return;
  }
  __shared__ double qrow[64];
  __shared__ u64 su[2048];
  __shared__ unsigned hist[256];
  __shared__ unsigned sA[256], sB[256];
  __shared__ unsigned s_bsel, s_larger;

  if (tid < 64) qrow[tid] = qs[(size_t)row * 64 + tid];
  __syncthreads();
  // ---- fp64 scores -> order-preserving u64 keys ----
  for (int jj = tid; jj <= t; jj += 256) {
    const double* kp = &ks[((size_t)(b * 2048 + jj)) * 64];
    double sc = 0.0;
    #pragma unroll
    for (int d2 = 0; d2 < 32; ++d2) {
      f64x2 kd = *(const f64x2*)&kp[d2 * 2];
      sc = fma(qrow[d2 * 2], kd.x, sc);
      sc = fma(qrow[d2 * 2 + 1], kd.y, sc);
    }
    u64 u = (u64)__double_as_longlong(sc);
    su[jj] = (u >> 63) ? ~u : (u | 0x8000000000000000ull);
  }
  __syncthreads();
  // ---- radix select: exact 64th-largest key ----
  u64 prefix = 0;
  int remaining = 64;
  for (int byte = 7; byte >= 0; --byte) {
    const int sh = byte * 8;
    hist[tid] = 0;
    __syncthreads();
    for (int jj = tid; jj <= t; jj += 256) {
      u64 u = su[jj];
      bool ok = (byte == 7) || (((u ^ prefix) >> (sh + 8)) == 0);
      if (ok) atomicAdd(&hist[(unsigned)((u >> sh) & 255)], 1u);
    }
    __syncthreads();
    // suffix-inclusive scan of hist via ping-pong shared scan (1 barrier/step)
    unsigned* sp = sA; unsigned* dp = sB;
    sp[tid] = hist[tid];
    __syncthreads();
    #pragma unroll
    for (int off = 1; off < 256; off <<= 1) {
      dp[tid] = sp[tid] + ((tid + off < 256) ? sp[tid + off] : 0u);
      __syncthreads();
      unsigned* tpp = sp; sp = dp; dp = tpp;
    }
    // sp[tid] = sum hist[tid..255]; non-increasing in tid.
    unsigned inc = sp[tid];
    unsigned cumAbove = (tid == 255) ? 0u : sp[tid + 1];
    if ((int)cumAbove < remaining && (int)inc >= remaining) {
      s_bsel = (unsigned)tid;   // unique: (cumAbove, inc] intervals are disjoint
      s_larger = cumAbove;
    }
    __syncthreads();
    prefix |= ((u64)s_bsel << sh);
    remaining -= (int)s_larger;
    __syncthreads();
  }
  // ---- deterministic compaction: thread owns jj in [tid*8, tid*8+8) ----
  const int c0 = tid * 8;
  unsigned cg = 0, ct_ = 0;
  #pragma unroll
  for (int e = 0; e < 8; ++e) {
    int jj = c0 + e;
    if (jj <= t) {
      u64 u = su[jj];
      cg += (u > prefix) ? 1u : 0u;
      ct_ += (u == prefix) ? 1u : 0u;
    }
  }
  const unsigned pack = cg | (ct_ << 16);
  {
    unsigned* sp = sA; unsigned* dp = sB;
    sp[tid] = pack;
    __syncthreads();
    #pragma unroll
    for (int off = 1; off < 256; off <<= 1) {
      dp[tid] = sp[tid] + ((tid >= off) ? sp[tid - off] : 0u);
      __syncthreads();
      unsigned* tpp = sp; sp = dp; dp = tpp;
    }
    // sp[tid] = inclusive prefix; sp[255] = totals
    const unsigned excl = sp[tid] - pack;
    const unsigned tot = sp[255];
    const unsigned Gtot = tot & 0xFFFFu;          // #strict-greater incl t
    const u64 ut = su[t];                          // LDS broadcast
    const unsigned gt = (ut > prefix) ? 1u : 0u;
    const unsigned tt = (ut == prefix) ? 1u : 0u;
    const int GtotX = (int)(Gtot - gt);           // greaters excluding t (t has max rank)
    int gpos = (int)(excl & 0xFFFFu);
    int tpos = (int)(excl >> 16);
    #pragma unroll
    for (int e = 0; e < 8; ++e) {
      int jj = c0 + e;
      if (jj > t) break;
      u64 u = su[jj];
      if (u > prefix) {
        if (jj != t) outp[1 + gpos] = jj;
        ++gpos;
      } else if (u == prefix) {
        if (jj != t && tpos < remaining) outp[1 + GtotX + tpos] = jj;
        ++tpos;
      }
    }
    if (tid == 0) {
      outp[0] = t;  // diagonal always first
      const unsigned Ttot = tot >> 16;
      int tb = (int)(Ttot - tt);                  // ties before t (t is last index)
      int emitT = tb < remaining ? tb : remaining;
      selcnt[row] = 1 + GtotX + emitT;            // 64 or 65
    }
  }
}

// ------------------------------------------------------------- sparse attention
__global__ __launch_bounds__(256) void k_attn(const f16* __restrict__ qr,
                                              const f16* __restrict__ kr,
                                              const f16* __restrict__ vv,
                                              const int* __restrict__ selcnt,
                                              const int* __restrict__ selidx,
                                              f16* __restrict__ y)
{
  const int blk = blockIdx.x;  // row*4 + kvh
  const int row = blk >> 2, kvh = blk & 3;
  const int b = row >> 11;
  const int tid = threadIdx.x, lane = tid & 63, wave = tid >> 6;
  const int cnt = selcnt[row];
  __shared__ int sidx[68];
  __shared__ f16 qlds[4][128];
  __shared__ float pl[4][66];
  if (tid < cnt) sidx[tid] = selidx[(size_t)row * 68 + tid];
  *(f16x2*)&qlds[wave][lane * 2] =
      *(const f16x2*)&qr[((size_t)row * 16 + kvh * 4 + wave) * 128 + lane * 2];
  __syncthreads();

  const float SCALE = 0.08838834764831845f;  // 1/sqrt(128)
  auto dotk = [&](int key) -> float {
    const f16* kp = &kr[((size_t)(b * 2048 + key)) * 512 + kvh * 128];
    float s = 0.0f;
    #pragma unroll
    for (int i = 0; i < 16; ++i) {
      f16x8 k8 = *(const f16x8*)&kp[i * 8];
      f16x8 q8 = *(const f16x8*)&qlds[wave][i * 8];
      #pragma unroll
      for (int e = 0; e < 8; ++e) s = fmaf((float)q8[e], (float)k8[e], s);
    }
    return s * SCALE;
  };

  float s1 = -__builtin_inff(), s2 = -__builtin_inff();
  if (lane < cnt) s1 = dotk(sidx[lane]);
  if (lane + 64 < cnt) s2 = dotk(sidx[lane + 64]);  // only lane 0, cnt==65
  float mx = fmaxf(s1, s2);
  #pragma unroll
  for (int off = 32; off; off >>= 1) mx = fmaxf(mx, __shfl_xor(mx, off));
  float p1 = (lane < cnt) ? __expf(s1 - mx) : 0.0f;
  float p2 = (lane + 64 < cnt) ? __expf(s2 - mx) : 0.0f;
  float l = p1 + p2;
  #pragma unroll
  for (int off = 32; off; off >>= 1) l += __shfl_xor(l, off);
  float linv = 1.0f / l;
  pl[wave][lane] = p1;
  if (lane == 0) pl[wave][64] = p2;
  __syncthreads();

  float y0 = 0.0f, y1 = 0.0f;
  const int d2 = lane * 2;
  for (int j = 0; j < cnt; ++j) {
    float p = pl[wave][j];
    int key = sidx[j];
    f16x2 v2 = *(const f16x2*)&vv[((size_t)(b * 2048 + key)) * 512 + kvh * 128 + d2];
    y0 = fmaf(p, (float)v2.x, y0);
    y1 = fmaf(p, (float)v2.y, y1);
  }
  y0 *= linv; y1 *= linv;
  f16x2 o; o.x = (f16)y0; o.y = (f16)y1;
  *(f16x2*)&y[(size_t)row * 2048 + (kvh * 4 + wave) * 128 + d2] = o;
}

// ================================================================ launch
extern "C" void kernel_launch(void* const* d_in, const int* in_sizes, int n_in,
                              void* d_out, int out_size, void* d_ws, size_t ws_size,
                              hipStream_t stream)
{
  (void)in_sizes; (void)n_in; (void)out_size; (void)ws_size;
  const float* x   = (const float*)d_in[0];
  const float* Wq  = (const float*)d_in[1];
  const float* bq  = (const float*)d_in[2];
  const float* Wkd = (const float*)d_in[3];
  const float* bkd = (const float*)d_in[4];
  const float* Wku = (const float*)d_in[5];
  const float* bku = (const float*)d_in[6];
  const float* Wo  = (const float*)d_in[7];
  const float* bo  = (const float*)d_in[8];
  float* out = (float*)d_out;

  char* ws = (char*)d_ws;
  size_t o = 0;
  auto alloc = [&](size_t bytes) -> void* {
    o = (o + 255) & ~(size_t)255;
    void* p = ws + o;
    o += bytes;
    return p;
  };
  f16* WqT   = (f16*)alloc(2048ull * 2048 * 2);
  f16* WoT   = (f16*)alloc(2048ull * 2048 * 2);
  f16* WkdT  = (f16*)alloc(512ull * 2048 * 2);
  f16* WkuT  = (f16*)alloc(1024ull * 512 * 2);
  f16* xh    = (f16*)alloc(4096ull * 2048 * 2);
  f16* qmain = (f16*)alloc(4096ull * 2048 * 2);  // reused as y after rope
  f16* kvh_  = (f16*)alloc(4096ull * 1024 * 2);
  f16* cbf   = (f16*)alloc(4096ull * 512 * 2);
  float* rc  = (float*)alloc(2048ull * 64 * 4);
  float* rs  = (float*)alloc(2048ull * 64 * 4);
  f16* qrope = (f16*)alloc(4096ull * 2048 * 2);
  f16* krope = (f16*)alloc(4096ull * 512 * 2);
  f16* vbf   = (f16*)alloc(4096ull * 512 * 2);
  int* selcnt = (int*)alloc(4096ull * 4);
  int* selidx = (int*)alloc(4096ull * 68 * 4);
  double* Bsel = (double*)alloc(2048ull * 128 * 8);
  double* bsel = (double*)alloc(128 * 8);
  double* qs64 = (double*)alloc(4096ull * 64 * 8);
  double* ks64 = (double*)alloc(4096ull * 64 * 8);
  f16* yh = qmain;  // alias: qmain dead after k_rope_q

  // --- weight prep ---
  k_transpose_cast<<<dim3(64, 64), 256, 0, stream>>>(Wq, WqT, 2048, 2048);
  k_transpose_cast<<<dim3(16, 64), 256, 0, stream>>>(Wkd, WkdT, 2048, 512);
  k_transpose_cast<<<dim3(32, 16), 256, 0, stream>>>(Wku, WkuT, 512, 1024);
  k_transpose_cast<<<dim3(64, 64), 256, 0, stream>>>(Wo, WoT, 2048, 2048);
  k_cast_f16<<<8192, 256, 0, stream>>>(x, xh, 2097152);

  // --- fp64 selector path ---
  k_prep_sel<<<2048, 64, 0, stream>>>(Wq, Wkd, Wku, Bsel);
  k_bias_sel<<<1, 128, 0, stream>>>(bq, bkd, Wku, bku, bsel);
  k_gemm_sel_f64<<<dim3(128, 2), 256, 0, stream>>>(x, Bsel, bsel, qs64, ks64);

  // --- fp16 MFMA main path ---
  k_gemm_bt<true><<<dim3(32, 16), 256, 0, stream>>>(xh, WqT, bq, nullptr, qmain,
                                                    4096, 2048, 2048, 2048, 2048, 2048);
  k_gemm_bt<true><<<dim3(32, 4), 256, 0, stream>>>(xh, WkdT, bkd, nullptr, cbf,
                                                   4096, 512, 2048, 2048, 2048, 512);
  k_gemm_bt<true><<<dim3(32, 8), 256, 0, stream>>>(cbf, WkuT, bku, nullptr, kvh_,
                                                   4096, 1024, 512, 512, 512, 1024);

  // --- RoPE ---
  k_rope_table<<<2048, 64, 0, stream>>>(rc, rs);
  k_rope_q<<<16384, 256, 0, stream>>>(qmain, rc, rs, qrope);
  k_rope_kv<<<4096, 256, 0, stream>>>(kvh_, rc, rs, krope, vbf);

  // --- selector top-k (fp64 exact, deterministic parallel select) ---
  k_topk64<<<4096, 256, 0, stream>>>(qs64, ks64, selcnt, selidx);

  // --- sparse attention ---
  k_attn<<<16384, 256, 0, stream>>>(qrope, krope, vbf, selcnt, selidx, yh);

  // --- output projection ---
  k_gemm_bt<false><<<dim3(32, 16), 256, 0, stream>>>(yh, WoT, bo, out, nullptr,
                                                     4096, 2048, 2048, 2048, 2048, 2048);
}

// Round 5
// 837.935 us; speedup vs baseline: 2.9782x; 1.0085x over previous
//
#include <hip/hip_runtime.h>

typedef unsigned int u32;
typedef unsigned long long u64;
typedef _Float16 f16;
typedef __attribute__((ext_vector_type(2))) _Float16 f16x2;
typedef __attribute__((ext_vector_type(4))) _Float16 f16x4;
typedef __attribute__((ext_vector_type(8))) _Float16 f16x8;
typedef __attribute__((ext_vector_type(4))) float f32x4;
typedef __attribute__((ext_vector_type(2))) double f64x2;

// Problem constants: B=2, T=2048, D=2048, LAT=512, H=16, HD=128, NKV=4, G=4,
// SEL_DIM=64, TOPK=64, NROW = 4096

// ------------------------------------------------- transpose + cast f32->f16
// out[C][R] = (f16) in[R][C]
__global__ __launch_bounds__(256) void k_transpose_cast(const float* __restrict__ in,
                                                        f16* __restrict__ out, int R, int C)
{
  __shared__ float tile[32][33];
  int c0 = blockIdx.x * 32, r0 = blockIdx.y * 32;
  int tx = threadIdx.x & 31, ty = threadIdx.x >> 5;  // ty 0..7
  #pragma unroll
  for (int i = ty; i < 32; i += 8) tile[i][tx] = in[(size_t)(r0 + i) * C + c0 + tx];
  __syncthreads();
  #pragma unroll
  for (int i = ty; i < 32; i += 8) out[(size_t)(c0 + i) * R + r0 + tx] = (f16)tile[tx][i];
}

// ------------------------------------------------------------- cast f32->f16
__global__ __launch_bounds__(256) void k_cast_f16(const float* __restrict__ in,
                                                  f16* __restrict__ out, int n4)
{
  int i = blockIdx.x * 256 + threadIdx.x;
  if (i >= n4) return;
  f32x4 v = *(const f32x4*)&in[(size_t)i * 4];
  f16x4 h; h.x = (f16)v.x; h.y = (f16)v.y; h.z = (f16)v.z; h.w = (f16)v.w;
  *(f16x4*)&out[(size_t)i * 4] = h;
}

// ------------------------------------------------------------- fp64 selector weights
// Bsel [2048][128]: cols 0..63 = Wq[:, :64] ; cols 64..127 = (Wkd @ Wku[:, :64]) in fp64
__global__ void k_prep_sel(const float* __restrict__ Wq, const float* __restrict__ Wkd,
                           const float* __restrict__ Wku, double* __restrict__ Bsel)
{
  const int k = blockIdx.x;   // 0..2047
  const int j = threadIdx.x;  // 0..63
  Bsel[(size_t)k * 128 + j] = (double)Wq[(size_t)k * 2048 + j];
  double s = 0.0;
  for (int l = 0; l < 512; ++l)
    s = fma((double)Wkd[(size_t)k * 512 + l], (double)Wku[(size_t)l * 1024 + j], s);
  Bsel[(size_t)k * 128 + 64 + j] = s;
}

__global__ void k_bias_sel(const float* __restrict__ bq, const float* __restrict__ bkd,
                           const float* __restrict__ Wku, const float* __restrict__ bku,
                           double* __restrict__ bsel)
{
  int j = threadIdx.x;  // 0..127
  if (j < 64) {
    bsel[j] = (double)bq[j];
  } else {
    int jj = j - 64;
    double s = (double)bku[jj];
    for (int l = 0; l < 512; ++l)
      s = fma((double)bkd[l], (double)Wku[(size_t)l * 1024 + jj], s);
    bsel[j] = s;
  }
}

// ------------------------------------------------------------- fp64 selector GEMM
// qs64/ks64 = x[4096][2048] @ Bsel[2048][128] + bsel.
__global__ __launch_bounds__(256) void k_gemm_sel_f64(const float* __restrict__ A,
                                                      const double* __restrict__ Bsel,
                                                      const double* __restrict__ bias,
                                                      double* __restrict__ qs64,
                                                      double* __restrict__ ks64)
{
  __shared__ double As[32][33];
  __shared__ double Bs[32][66];
  const int m0 = blockIdx.x * 32, n0 = blockIdx.y * 64;
  const int tid = threadIdx.x;
  const int tx = tid & 15, ty = tid >> 4;
  const int ar = tid >> 3, ac4 = (tid & 7) * 4;
  double acc[2][4] = {};

  f32x4 aN = *(const f32x4*)&A[(size_t)(m0 + ar) * 2048 + ac4];
  f64x2 bN[4];
  #pragma unroll
  for (int it = 0; it < 4; ++it) {
    int c = it * 256 + tid; int kk = c >> 5, n2 = (c & 31) * 2;
    bN[it] = *(const f64x2*)&Bsel[(size_t)kk * 128 + n0 + n2];
  }
  for (int k0 = 0; k0 < 2048; k0 += 32) {
    __syncthreads();
    As[ar][ac4] = (double)aN.x; As[ar][ac4 + 1] = (double)aN.y;
    As[ar][ac4 + 2] = (double)aN.z; As[ar][ac4 + 3] = (double)aN.w;
    #pragma unroll
    for (int it = 0; it < 4; ++it) {
      int c = it * 256 + tid; int kk = c >> 5, n2 = (c & 31) * 2;
      Bs[kk][n2] = bN[it].x; Bs[kk][n2 + 1] = bN[it].y;
    }
    __syncthreads();
    if (k0 + 32 < 2048) {
      aN = *(const f32x4*)&A[(size_t)(m0 + ar) * 2048 + k0 + 32 + ac4];
      #pragma unroll
      for (int it = 0; it < 4; ++it) {
        int c = it * 256 + tid; int kk = c >> 5, n2 = (c & 31) * 2;
        bN[it] = *(const f64x2*)&Bsel[(size_t)(k0 + 32 + kk) * 128 + n0 + n2];
      }
    }
    #pragma unroll
    for (int kk = 0; kk < 32; ++kk) {
      double a0 = As[ty * 2][kk], a1 = As[ty * 2 + 1][kk];
      f64x2 b01 = *(const f64x2*)&Bs[kk][tx * 4];
      f64x2 b23 = *(const f64x2*)&Bs[kk][tx * 4 + 2];
      acc[0][0] = fma(a0, b01.x, acc[0][0]); acc[0][1] = fma(a0, b01.y, acc[0][1]);
      acc[0][2] = fma(a0, b23.x, acc[0][2]); acc[0][3] = fma(a0, b23.y, acc[0][3]);
      acc[1][0] = fma(a1, b01.x, acc[1][0]); acc[1][1] = fma(a1, b01.y, acc[1][1]);
      acc[1][2] = fma(a1, b23.x, acc[1][2]); acc[1][3] = fma(a1, b23.y, acc[1][3]);
    }
  }
  #pragma unroll
  for (int i = 0; i < 2; ++i) {
    int row = m0 + ty * 2 + i;
    #pragma unroll
    for (int j = 0; j < 4; ++j) {
      int n = n0 + tx * 4 + j;
      double v = acc[i][j] + bias[n];
      if (n < 64) qs64[(size_t)row * 64 + n] = v;
      else        ks64[(size_t)row * 64 + (n - 64)] = v;
    }
  }
}

// ------------------------------------------------------------- fp16 MFMA GEMM (m97 structure)
// C[M][N] = A[M][K] @ BT[N][K]^T + bias.  128x128 tile, BK=64, 4 waves, global_load_lds(16B).
template <bool OUTF16>
__global__ __launch_bounds__(256) void k_gemm_bt(const f16* __restrict__ A,
                                                 const f16* __restrict__ BT,
                                                 const float* __restrict__ bias,
                                                 float* __restrict__ C, f16* __restrict__ Ch,
                                                 int M, int N, int K, int lda, int ldb, int ldc)
{
  __shared__ __align__(16) f16 As[128 * 64];
  __shared__ __align__(16) f16 Bs[128 * 64];
  const int tid = threadIdx.x;
  const int lane = tid & 63;
  const int wave = tid >> 6;
  const int m0 = blockIdx.x * 128, n0 = blockIdx.y * 128;
  const int wr = (wave >> 1) * 64, wc = (wave & 1) * 64;
  const int lrow = lane & 15;
  const int kgrp = (lane >> 4) * 8;
  f32x4 acc[4][4] = {};

  for (int k0 = 0; k0 < K; k0 += 64) {
    __syncthreads();
    #pragma unroll
    for (int it = 0; it < 4; ++it) {
      int c = it * 256 + tid;
      int r = c >> 3, c8 = (c & 7) * 8;
      int lbase = (it * 256 + (tid & 192)) * 8;  // wave-uniform LDS offset
      const f16* ga = A + (size_t)(m0 + r) * lda + k0 + c8;
      __builtin_amdgcn_global_load_lds((const __attribute__((address_space(1))) u32*)ga,
                                       (__attribute__((address_space(3))) u32*)&As[lbase],
                                       16, 0, 0);
      const f16* gb = BT + (size_t)(n0 + r) * ldb + k0 + c8;
      __builtin_amdgcn_global_load_lds((const __attribute__((address_space(1))) u32*)gb,
                                       (__attribute__((address_space(3))) u32*)&Bs[lbase],
                                       16, 0, 0);
    }
    __syncthreads();
    #pragma unroll
    for (int ks = 0; ks < 2; ++ks) {
      f16x8 af[4], bfr[4];
      #pragma unroll
      for (int m = 0; m < 4; ++m)
        af[m] = *(const f16x8*)&As[(wr + m * 16 + lrow) * 64 + ks * 32 + kgrp];
      #pragma unroll
      for (int n = 0; n < 4; ++n)
        bfr[n] = *(const f16x8*)&Bs[(wc + n * 16 + lrow) * 64 + ks * 32 + kgrp];
      #pragma unroll
      for (int m = 0; m < 4; ++m)
        #pragma unroll
        for (int n = 0; n < 4; ++n)
          acc[m][n] = __builtin_amdgcn_mfma_f32_16x16x32_f16(af[m], bfr[n], acc[m][n], 0, 0, 0);
    }
  }
  const int rbase = m0 + wr + (lane >> 4) * 4;  // C/D: col=lane&15, row=(lane>>4)*4+reg [m89]
  #pragma unroll
  for (int n = 0; n < 4; ++n) {
    int col = n0 + wc + n * 16 + lrow;
    float bv = bias ? bias[col] : 0.0f;
    #pragma unroll
    for (int m = 0; m < 4; ++m) {
      #pragma unroll
      for (int j = 0; j < 4; ++j) {
        int rowi = rbase + m * 16 + j;
        float v = acc[m][n][j] + bv;
        if (OUTF16) Ch[(size_t)rowi * ldc + col] = (f16)v;
        else        C[(size_t)rowi * ldc + col] = v;
      }
    }
  }
}

// ------------------------------------------------------------- RoPE tables
__global__ void k_rope_table(float* __restrict__ rc, float* __restrict__ rs)
{
  int t = blockIdx.x, i = threadIdx.x;  // 2048 x 64
  int fi = (2 * i) & 63;
  double inv = pow(10000.0, -(double)fi / 64.0);
  double a = (double)t * inv;
  rc[t * 64 + i] = (float)cos(a);
  rs[t * 64 + i] = (float)sin(a);
}

__global__ __launch_bounds__(256) void k_rope_q(const f16* __restrict__ q,
                                                const float* __restrict__ rc,
                                                const float* __restrict__ rs,
                                                f16* __restrict__ out)
{
  int g = blockIdx.x * 256 + threadIdx.x;  // 4096*16*64
  int row = g >> 10, rem = g & 1023;
  int h = rem >> 6, i = rem & 63;
  int t = row & 2047;
  size_t base = (size_t)row * 2048 + h * 128 + 2 * i;
  f16x2 v = *(const f16x2*)&q[base];
  float x1 = (float)v.x, x2 = (float)v.y;
  float c = rc[t * 64 + i], s = rs[t * 64 + i];
  f16x2 o; o.x = (f16)(x1 * c - x2 * s); o.y = (f16)(x1 * s + x2 * c);
  *(f16x2*)&out[base] = o;
}

__global__ __launch_bounds__(256) void k_rope_kv(const f16* __restrict__ kv,
                                                 const float* __restrict__ rc,
                                                 const float* __restrict__ rs,
                                                 f16* __restrict__ kout, f16* __restrict__ vout)
{
  int g = blockIdx.x * 256 + threadIdx.x;  // 4096*4*64
  int row = g >> 8, rem = g & 255;
  int kvh = rem >> 6, i = rem & 63;
  int t = row & 2047;
  size_t kb = (size_t)row * 1024 + kvh * 128 + 2 * i;
  f16x2 kvp = *(const f16x2*)&kv[kb];
  float x1 = (float)kvp.x, x2 = (float)kvp.y;
  float c = rc[t * 64 + i], s = rs[t * 64 + i];
  size_t ob = (size_t)row * 512 + kvh * 128 + 2 * i;
  f16x2 ko; ko.x = (f16)(x1 * c - x2 * s); ko.y = (f16)(x1 * s + x2 * c);
  *(f16x2*)&kout[ob] = ko;
  f16x2 vp = *(const f16x2*)&kv[(size_t)row * 1024 + 512 + kvh * 128 + 2 * i];
  *(f16x2*)&vout[ob] = vp;
}

// ------------------------------------------------------------- exact top-64, fp64 scores
// Deterministic parallel select (R4 structure, proven on-device) + EARLY EXIT:
// stop radix passes once the selected bin holds <=128 candidates (typically pass 1),
// then resolve the exact 64th-largest key among candidates by parallel ranking.
// Histogram atomics are pre-aggregated per thread to kill the pass-1 same-bin storm.
// Semantics identical: top-64 by fp64 score, ties lowest-index first, diagonal forced.
__global__ __launch_bounds__(256) void k_topk64(const double* __restrict__ qs,
                                                const double* __restrict__ ks,
                                                int* __restrict__ selcnt,
                                                int* __restrict__ selidx)
{
  const int row = blockIdx.x;
  const int b = row >> 11, t = row & 2047;
  const int tid = threadIdx.x;
  int* outp = selidx + (size_t)row * 68;
  if (t < 64) {  // all causal positions selected
    for (int jj = tid; jj <= t; jj += 256) outp[jj] = jj;
    if (tid == 0) selcnt[row] = t + 1;
    return;
  }
  __shared__ double qrow[64];
  __shared__ u64 su[2048];
  __shared__ unsigned hist[256];
  __shared__ unsigned sA[256], sB[256];
  __shared__ unsigned s_bsel, s_larger, s_cnt;
  __shared__ u64 s_thr;
  __shared__ int s_remfin;
  __shared__ int cand[128];
  __shared__ u64 ckey[128];

  if (tid < 64) qrow[tid] = qs[(size_t)row * 64 + tid];
  __syncthreads();
  // ---- fp64 scores -> order-preserving u64 keys ----
  for (int jj = tid; jj <= t; jj += 256) {
    const double* kp = &ks[((size_t)(b * 2048 + jj)) * 64];
    double sc = 0.0;
    #pragma unroll
    for (int d2 = 0; d2 < 32; ++d2) {
      f64x2 kd = *(const f64x2*)&kp[d2 * 2];
      sc = fma(qrow[d2 * 2], kd.x, sc);
      sc = fma(qrow[d2 * 2 + 1], kd.y, sc);
    }
    u64 u = (u64)__double_as_longlong(sc);
    su[jj] = (u >> 63) ? ~u : (u | 0x8000000000000000ull);
  }
  __syncthreads();
  // ---- radix select with early exit ----
  const int c0 = tid * 8;
  u64 prefix = 0;
  int remaining = 64;
  int broke = 0, sh_final = 0;
  for (int byte = 7; byte >= 0; --byte) {
    const int sh = byte * 8;
    hist[tid] = 0;
    __syncthreads();
    {
      // per-thread pre-aggregated histogram update (static indexing only)
      unsigned bn[8]; bool vl[8];
      #pragma unroll
      for (int e = 0; e < 8; ++e) {
        int jj = c0 + e;
        u64 u = (jj <= t) ? su[jj] : 0;
        bool ok = (jj <= t) && ((byte == 7) || (((u ^ prefix) >> (sh + 8)) == 0));
        bn[e] = (unsigned)((u >> sh) & 255);
        vl[e] = ok;
      }
      #pragma unroll
      for (int e = 0; e < 8; ++e) {
        if (vl[e]) {
          bool first = true;
          #pragma unroll
          for (int p = 0; p < 8; ++p)
            if (p < e && vl[p] && bn[p] == bn[e]) first = false;
          if (first) {
            unsigned c = 0;
            #pragma unroll
            for (int q = 0; q < 8; ++q)
              if (q >= e && vl[q] && bn[q] == bn[e]) ++c;
            atomicAdd(&hist[bn[e]], c);
          }
        }
      }
    }
    __syncthreads();
    // suffix-inclusive scan of hist (ping-pong, barrier-stepped)
    unsigned* sp = sA; unsigned* dp = sB;
    sp[tid] = hist[tid];
    __syncthreads();
    #pragma unroll
    for (int off = 1; off < 256; off <<= 1) {
      dp[tid] = sp[tid] + ((tid + off < 256) ? sp[tid + off] : 0u);
      __syncthreads();
      unsigned* tpp = sp; sp = dp; dp = tpp;
    }
    unsigned inc = sp[tid];
    unsigned cumAbove = (tid == 255) ? 0u : sp[tid + 1];
    if ((int)cumAbove < remaining && (int)inc >= remaining) {
      s_bsel = (unsigned)tid;   // unique straddling thread
      s_larger = cumAbove;
      s_cnt = inc - cumAbove;   // keys matching prefix incl. this byte
    }
    __syncthreads();
    prefix |= ((u64)s_bsel << sh);
    remaining -= (int)s_larger;
    int cnt = (int)s_cnt;
    __syncthreads();
    if (cnt <= 128) { broke = 1; sh_final = sh; break; }  // uniform branch
  }
  // ---- resolve exact 64th-largest key among candidates ----
  u64 thr;
  int remfin;
  if (broke) {
    // deterministic index-ordered compaction of candidates (prefix match at sh_final)
    unsigned cg = 0;
    #pragma unroll
    for (int e = 0; e < 8; ++e) {
      int jj = c0 + e;
      if (jj <= t && (((su[jj] ^ prefix) >> sh_final) == 0)) ++cg;
    }
    unsigned* sp = sA; unsigned* dp = sB;
    sp[tid] = cg;
    __syncthreads();
    #pragma unroll
    for (int off = 1; off < 256; off <<= 1) {
      dp[tid] = sp[tid] + ((tid >= off) ? sp[tid - off] : 0u);
      __syncthreads();
      unsigned* tpp = sp; sp = dp; dp = tpp;
    }
    const int C = (int)sp[255];
    int pos = (int)(sp[tid] - cg);
    #pragma unroll
    for (int e = 0; e < 8; ++e) {
      int jj = c0 + e;
      if (jj <= t && (((su[jj] ^ prefix) >> sh_final) == 0)) cand[pos++] = jj;
    }
    __syncthreads();
    if (tid < C) ckey[tid] = su[cand[tid]];
    __syncthreads();
    if (tid < C) {
      u64 k = ckey[tid];
      int g = 0, eq = 0;
      for (int j = 0; j < C; ++j) {
        g += (ckey[j] > k) ? 1 : 0;
        eq += (ckey[j] == k) ? 1 : 0;
      }
      if (g < remaining && remaining <= g + eq) {  // straddling key (all writers agree)
        s_thr = k;
        s_remfin = remaining - g;
      }
    }
    __syncthreads();
    thr = s_thr;
    remfin = s_remfin;
  } else {
    thr = prefix;     // full 64-bit prefix is the exact 64th key
    remfin = remaining;
  }
  __syncthreads();
  // ---- deterministic emit: diag, greaters asc, first remfin ties asc ----
  unsigned cg = 0, ct_ = 0;
  #pragma unroll
  for (int e = 0; e < 8; ++e) {
    int jj = c0 + e;
    if (jj <= t) {
      u64 u = su[jj];
      cg += (u > thr) ? 1u : 0u;
      ct_ += (u == thr) ? 1u : 0u;
    }
  }
  const unsigned pack = cg | (ct_ << 16);
  {
    unsigned* sp = sA; unsigned* dp = sB;
    sp[tid] = pack;
    __syncthreads();
    #pragma unroll
    for (int off = 1; off < 256; off <<= 1) {
      dp[tid] = sp[tid] + ((tid >= off) ? sp[tid - off] : 0u);
      __syncthreads();
      unsigned* tpp = sp; sp = dp; dp = tpp;
    }
    const unsigned excl = sp[tid] - pack;
    const unsigned tot = sp[255];
    const unsigned Gtot = tot & 0xFFFFu;          // #strict-greater incl t
    const u64 ut = su[t];
    const unsigned gt = (ut > thr) ? 1u : 0u;
    const unsigned tt = (ut == thr) ? 1u : 0u;
    const int GtotX = (int)(Gtot - gt);           // greaters excluding t
    int gpos = (int)(excl & 0xFFFFu);
    int tpos = (int)(excl >> 16);
    #pragma unroll
    for (int e = 0; e < 8; ++e) {
      int jj = c0 + e;
      if (jj > t) break;
      u64 u = su[jj];
      if (u > thr) {
        if (jj != t) outp[1 + gpos] = jj;
        ++gpos;
      } else if (u == thr) {
        if (jj != t && tpos < remfin) outp[1 + GtotX + tpos] = jj;
        ++tpos;
      }
    }
    if (tid == 0) {
      outp[0] = t;  // diagonal always first
      const unsigned Ttot = tot >> 16;
      int tb = (int)(Ttot - tt);                  // ties before t
      int emitT = tb < remfin ? tb : remfin;
      selcnt[row] = 1 + GtotX + emitT;            // 64 or 65
    }
  }
}

// ------------------------------------------------------------- sparse attention
__global__ __launch_bounds__(256) void k_attn(const f16* __restrict__ qr,
                                              const f16* __restrict__ kr,
                                              const f16* __restrict__ vv,
                                              const int* __restrict__ selcnt,
                                              const int* __restrict__ selidx,
                                              f16* __restrict__ y)
{
  const int blk = blockIdx.x;  // row*4 + kvh
  const int row = blk >> 2, kvh = blk & 3;
  const int b = row >> 11;
  const int tid = threadIdx.x, lane = tid & 63, wave = tid >> 6;
  const int cnt = selcnt[row];
  __shared__ int sidx[68];
  __shared__ f16 qlds[4][128];
  __shared__ float pl[4][66];
  if (tid < cnt) sidx[tid] = selidx[(size_t)row * 68 + tid];
  *(f16x2*)&qlds[wave][lane * 2] =
      *(const f16x2*)&qr[((size_t)row * 16 + kvh * 4 + wave) * 128 + lane * 2];
  __syncthreads();

  const float SCALE = 0.08838834764831845f;  // 1/sqrt(128)
  auto dotk = [&](int key) -> float {
    const f16* kp = &kr[((size_t)(b * 2048 + key)) * 512 + kvh * 128];
    float s = 0.0f;
    #pragma unroll
    for (int i = 0; i < 16; ++i) {
      f16x8 k8 = *(const f16x8*)&kp[i * 8];
      f16x8 q8 = *(const f16x8*)&qlds[wave][i * 8];
      #pragma unroll
      for (int e = 0; e < 8; ++e) s = fmaf((float)q8[e], (float)k8[e], s);
    }
    return s * SCALE;
  };

  float s1 = -__builtin_inff(), s2 = -__builtin_inff();
  if (lane < cnt) s1 = dotk(sidx[lane]);
  if (lane + 64 < cnt) s2 = dotk(sidx[lane + 64]);  // only lane 0, cnt==65
  float mx = fmaxf(s1, s2);
  #pragma unroll
  for (int off = 32; off; off >>= 1) mx = fmaxf(mx, __shfl_xor(mx, off));
  float p1 = (lane < cnt) ? __expf(s1 - mx) : 0.0f;
  float p2 = (lane + 64 < cnt) ? __expf(s2 - mx) : 0.0f;
  float l = p1 + p2;
  #pragma unroll
  for (int off = 32; off; off >>= 1) l += __shfl_xor(l, off);
  float linv = 1.0f / l;
  pl[wave][lane] = p1;
  if (lane == 0) pl[wave][64] = p2;
  __syncthreads();

  float y0 = 0.0f, y1 = 0.0f;
  const int d2 = lane * 2;
  for (int j = 0; j < cnt; ++j) {
    float p = pl[wave][j];
    int key = sidx[j];
    f16x2 v2 = *(const f16x2*)&vv[((size_t)(b * 2048 + key)) * 512 + kvh * 128 + d2];
    y0 = fmaf(p, (float)v2.x, y0);
    y1 = fmaf(p, (float)v2.y, y1);
  }
  y0 *= linv; y1 *= linv;
  f16x2 o; o.x = (f16)y0; o.y = (f16)y1;
  *(f16x2*)&y[(size_t)row * 2048 + (kvh * 4 + wave) * 128 + d2] = o;
}

// ================================================================ launch
extern "C" void kernel_launch(void* const* d_in, const int* in_sizes, int n_in,
                              void* d_out, int out_size, void* d_ws, size_t ws_size,
                              hipStream_t stream)
{
  (void)in_sizes; (void)n_in; (void)out_size; (void)ws_size;
  const float* x   = (const float*)d_in[0];
  const float* Wq  = (const float*)d_in[1];
  const float* bq  = (const float*)d_in[2];
  const float* Wkd = (const float*)d_in[3];
  const float* bkd = (const float*)d_in[4];
  const float* Wku = (const float*)d_in[5];
  const float* bku = (const float*)d_in[6];
  const float* Wo  = (const float*)d_in[7];
  const float* bo  = (const float*)d_in[8];
  float* out = (float*)d_out;

  char* ws = (char*)d_ws;
  size_t o = 0;
  auto alloc = [&](size_t bytes) -> void* {
    o = (o + 255) & ~(size_t)255;
    void* p = ws + o;
    o += bytes;
    return p;
  };
  f16* WqT   = (f16*)alloc(2048ull * 2048 * 2);
  f16* WoT   = (f16*)alloc(2048ull * 2048 * 2);
  f16* WkdT  = (f16*)alloc(512ull * 2048 * 2);
  f16* WkuT  = (f16*)alloc(1024ull * 512 * 2);
  f16* xh    = (f16*)alloc(4096ull * 2048 * 2);
  f16* qmain = (f16*)alloc(4096ull * 2048 * 2);  // reused as y after rope
  f16* kvh_  = (f16*)alloc(4096ull * 1024 * 2);
  f16* cbf   = (f16*)alloc(4096ull * 512 * 2);
  float* rc  = (float*)alloc(2048ull * 64 * 4);
  float* rs  = (float*)alloc(2048ull * 64 * 4);
  f16* qrope = (f16*)alloc(4096ull * 2048 * 2);
  f16* krope = (f16*)alloc(4096ull * 512 * 2);
  f16* vbf   = (f16*)alloc(4096ull * 512 * 2);
  int* selcnt = (int*)alloc(4096ull * 4);
  int* selidx = (int*)alloc(4096ull * 68 * 4);
  double* Bsel = (double*)alloc(2048ull * 128 * 8);
  double* bsel = (double*)alloc(128 * 8);
  double* qs64 = (double*)alloc(4096ull * 64 * 8);
  double* ks64 = (double*)alloc(4096ull * 64 * 8);
  f16* yh = qmain;  // alias: qmain dead after k_rope_q

  // --- weight prep ---
  k_transpose_cast<<<dim3(64, 64), 256, 0, stream>>>(Wq, WqT, 2048, 2048);
  k_transpose_cast<<<dim3(16, 64), 256, 0, stream>>>(Wkd, WkdT, 2048, 512);
  k_transpose_cast<<<dim3(32, 16), 256, 0, stream>>>(Wku, WkuT, 512, 1024);
  k_transpose_cast<<<dim3(64, 64), 256, 0, stream>>>(Wo, WoT, 2048, 2048);
  k_cast_f16<<<8192, 256, 0, stream>>>(x, xh, 2097152);

  // --- fp64 selector path ---
  k_prep_sel<<<2048, 64, 0, stream>>>(Wq, Wkd, Wku, Bsel);
  k_bias_sel<<<1, 128, 0, stream>>>(bq, bkd, Wku, bku, bsel);
  k_gemm_sel_f64<<<dim3(128, 2), 256, 0, stream>>>(x, Bsel, bsel, qs64, ks64);

  // --- fp16 MFMA main path ---
  k_gemm_bt<true><<<dim3(32, 16), 256, 0, stream>>>(xh, WqT, bq, nullptr, qmain,
                                                    4096, 2048, 2048, 2048, 2048, 2048);
  k_gemm_bt<true><<<dim3(32, 4), 256, 0, stream>>>(xh, WkdT, bkd, nullptr, cbf,
                                                   4096, 512, 2048, 2048, 2048, 512);
  k_gemm_bt<true><<<dim3(32, 8), 256, 0, stream>>>(cbf, WkuT, bku, nullptr, kvh_,
                                                   4096, 1024, 512, 512, 512, 1024);

  // --- RoPE ---
  k_rope_table<<<2048, 64, 0, stream>>>(rc, rs);
  k_rope_q<<<16384, 256, 0, stream>>>(qmain, rc, rs, qrope);
  k_rope_kv<<<4096, 256, 0, stream>>>(kvh_, rc, rs, krope, vbf);

  // --- selector top-k (fp64 exact, early-exit deterministic select) ---
  k_topk64<<<4096, 256, 0, stream>>>(qs64, ks64, selcnt, selidx);

  // --- sparse attention ---
  k_attn<<<16384, 256, 0, stream>>>(qrope, krope, vbf, selcnt, selidx, yh);

  // --- output projection ---
  k_gemm_bt<false><<<dim3(32, 16), 256, 0, stream>>>(yh, WoT, bo, out, nullptr,
                                                     4096, 2048, 2048, 2048, 2048, 2048);
}

// Round 6
// 648.874 us; speedup vs baseline: 3.8459x; 1.2914x over previous
//
#include <hip/hip_runtime.h>

typedef unsigned int u32;
typedef unsigned long long u64;
typedef _Float16 f16;
typedef __attribute__((ext_vector_type(2))) _Float16 f16x2;
typedef __attribute__((ext_vector_type(4))) _Float16 f16x4;
typedef __attribute__((ext_vector_type(8))) _Float16 f16x8;
typedef __attribute__((ext_vector_type(4))) float f32x4;
typedef __attribute__((ext_vector_type(2))) double f64x2;

// Problem constants: B=2, T=2048, D=2048, LAT=512, H=16, HD=128, NKV=4, G=4,
// SEL_DIM=64, TOPK=64, NROW = 4096

// su storage swizzle: spreads the tid*8+e LDS sweep across 16 banks (bijective
// within each 16-element group: XOR of low-3 bits by bits 4..6).
__device__ __forceinline__ int suX(int jj) { return jj ^ ((jj >> 4) & 7); }

// ------------------------------------------------- transpose + cast f32->f16
// out[C][R] = (f16) in[R][C]
__global__ __launch_bounds__(256) void k_transpose_cast(const float* __restrict__ in,
                                                        f16* __restrict__ out, int R, int C)
{
  __shared__ float tile[32][33];
  int c0 = blockIdx.x * 32, r0 = blockIdx.y * 32;
  int tx = threadIdx.x & 31, ty = threadIdx.x >> 5;  // ty 0..7
  #pragma unroll
  for (int i = ty; i < 32; i += 8) tile[i][tx] = in[(size_t)(r0 + i) * C + c0 + tx];
  __syncthreads();
  #pragma unroll
  for (int i = ty; i < 32; i += 8) out[(size_t)(c0 + i) * R + r0 + tx] = (f16)tile[tx][i];
}

// ------------------------------------------------------------- cast f32->f16
__global__ __launch_bounds__(256) void k_cast_f16(const float* __restrict__ in,
                                                  f16* __restrict__ out, int n4)
{
  int i = blockIdx.x * 256 + threadIdx.x;
  if (i >= n4) return;
  f32x4 v = *(const f32x4*)&in[(size_t)i * 4];
  f16x4 h; h.x = (f16)v.x; h.y = (f16)v.y; h.z = (f16)v.z; h.w = (f16)v.w;
  *(f16x4*)&out[(size_t)i * 4] = h;
}

// ------------------------------------------------------------- fp64 selector weights
__global__ void k_prep_sel(const float* __restrict__ Wq, const float* __restrict__ Wkd,
                           const float* __restrict__ Wku, double* __restrict__ Bsel)
{
  const int k = blockIdx.x;   // 0..2047
  const int j = threadIdx.x;  // 0..63
  Bsel[(size_t)k * 128 + j] = (double)Wq[(size_t)k * 2048 + j];
  double s = 0.0;
  for (int l = 0; l < 512; ++l)
    s = fma((double)Wkd[(size_t)k * 512 + l], (double)Wku[(size_t)l * 1024 + j], s);
  Bsel[(size_t)k * 128 + 64 + j] = s;
}

__global__ void k_bias_sel(const float* __restrict__ bq, const float* __restrict__ bkd,
                           const float* __restrict__ Wku, const float* __restrict__ bku,
                           double* __restrict__ bsel)
{
  int j = threadIdx.x;  // 0..127
  if (j < 64) {
    bsel[j] = (double)bq[j];
  } else {
    int jj = j - 64;
    double s = (double)bku[jj];
    for (int l = 0; l < 512; ++l)
      s = fma((double)bkd[l], (double)Wku[(size_t)l * 1024 + jj], s);
    bsel[j] = s;
  }
}

// ------------------------------------------------------------- fp64 selector GEMM
// qs64/ks64 = x[4096][2048] @ Bsel[2048][128] + bsel.
__global__ __launch_bounds__(256) void k_gemm_sel_f64(const float* __restrict__ A,
                                                      const double* __restrict__ Bsel,
                                                      const double* __restrict__ bias,
                                                      double* __restrict__ qs64,
                                                      double* __restrict__ ks64)
{
  __shared__ double As[32][33];
  __shared__ double Bs[32][66];
  const int m0 = blockIdx.x * 32, n0 = blockIdx.y * 64;
  const int tid = threadIdx.x;
  const int tx = tid & 15, ty = tid >> 4;
  const int ar = tid >> 3, ac4 = (tid & 7) * 4;
  double acc[2][4] = {};

  f32x4 aN = *(const f32x4*)&A[(size_t)(m0 + ar) * 2048 + ac4];
  f64x2 bN[4];
  #pragma unroll
  for (int it = 0; it < 4; ++it) {
    int c = it * 256 + tid; int kk = c >> 5, n2 = (c & 31) * 2;
    bN[it] = *(const f64x2*)&Bsel[(size_t)kk * 128 + n0 + n2];
  }
  for (int k0 = 0; k0 < 2048; k0 += 32) {
    __syncthreads();
    As[ar][ac4] = (double)aN.x; As[ar][ac4 + 1] = (double)aN.y;
    As[ar][ac4 + 2] = (double)aN.z; As[ar][ac4 + 3] = (double)aN.w;
    #pragma unroll
    for (int it = 0; it < 4; ++it) {
      int c = it * 256 + tid; int kk = c >> 5, n2 = (c & 31) * 2;
      Bs[kk][n2] = bN[it].x; Bs[kk][n2 + 1] = bN[it].y;
    }
    __syncthreads();
    if (k0 + 32 < 2048) {
      aN = *(const f32x4*)&A[(size_t)(m0 + ar) * 2048 + k0 + 32 + ac4];
      #pragma unroll
      for (int it = 0; it < 4; ++it) {
        int c = it * 256 + tid; int kk = c >> 5, n2 = (c & 31) * 2;
        bN[it] = *(const f64x2*)&Bsel[(size_t)(k0 + 32 + kk) * 128 + n0 + n2];
      }
    }
    #pragma unroll
    for (int kk = 0; kk < 32; ++kk) {
      double a0 = As[ty * 2][kk], a1 = As[ty * 2 + 1][kk];
      f64x2 b01 = *(const f64x2*)&Bs[kk][tx * 4];
      f64x2 b23 = *(const f64x2*)&Bs[kk][tx * 4 + 2];
      acc[0][0] = fma(a0, b01.x, acc[0][0]); acc[0][1] = fma(a0, b01.y, acc[0][1]);
      acc[0][2] = fma(a0, b23.x, acc[0][2]); acc[0][3] = fma(a0, b23.y, acc[0][3]);
      acc[1][0] = fma(a1, b01.x, acc[1][0]); acc[1][1] = fma(a1, b01.y, acc[1][1]);
      acc[1][2] = fma(a1, b23.x, acc[1][2]); acc[1][3] = fma(a1, b23.y, acc[1][3]);
    }
  }
  #pragma unroll
  for (int i = 0; i < 2; ++i) {
    int row = m0 + ty * 2 + i;
    #pragma unroll
    for (int j = 0; j < 4; ++j) {
      int n = n0 + tx * 4 + j;
      double v = acc[i][j] + bias[n];
      if (n < 64) qs64[(size_t)row * 64 + n] = v;
      else        ks64[(size_t)row * 64 + (n - 64)] = v;
    }
  }
}

// ------------------------------------------------------------- fp64 transpose
// ks64 [2][2048][64] -> ksT [2][64][2048]  (coalesced both sides)
__global__ __launch_bounds__(256) void k_transpose64(const double* __restrict__ in,
                                                     double* __restrict__ out)
{
  __shared__ double tile[32][33];
  const int bt = blockIdx.z;
  const int c0 = blockIdx.x * 32;  // 0 or 32 of the 64 cols
  const int r0 = blockIdx.y * 32;  // of 2048 rows
  int tx = threadIdx.x & 31, ty = threadIdx.x >> 5;
  const double* ip = in + (size_t)bt * 2048 * 64;
  double* op = out + (size_t)bt * 64 * 2048;
  #pragma unroll
  for (int i = ty; i < 32; i += 8) tile[i][tx] = ip[(size_t)(r0 + i) * 64 + c0 + tx];
  __syncthreads();
  #pragma unroll
  for (int i = ty; i < 32; i += 8) op[(size_t)(c0 + i) * 2048 + r0 + tx] = tile[tx][i];
}

// ------------------------------------------------------------- fp16 MFMA GEMM (m97 structure)
template <bool OUTF16>
__global__ __launch_bounds__(256) void k_gemm_bt(const f16* __restrict__ A,
                                                 const f16* __restrict__ BT,
                                                 const float* __restrict__ bias,
                                                 float* __restrict__ C, f16* __restrict__ Ch,
                                                 int M, int N, int K, int lda, int ldb, int ldc)
{
  __shared__ __align__(16) f16 As[128 * 64];
  __shared__ __align__(16) f16 Bs[128 * 64];
  const int tid = threadIdx.x;
  const int lane = tid & 63;
  const int wave = tid >> 6;
  const int m0 = blockIdx.x * 128, n0 = blockIdx.y * 128;
  const int wr = (wave >> 1) * 64, wc = (wave & 1) * 64;
  const int lrow = lane & 15;
  const int kgrp = (lane >> 4) * 8;
  f32x4 acc[4][4] = {};

  for (int k0 = 0; k0 < K; k0 += 64) {
    __syncthreads();
    #pragma unroll
    for (int it = 0; it < 4; ++it) {
      int c = it * 256 + tid;
      int r = c >> 3, c8 = (c & 7) * 8;
      int lbase = (it * 256 + (tid & 192)) * 8;  // wave-uniform LDS offset
      const f16* ga = A + (size_t)(m0 + r) * lda + k0 + c8;
      __builtin_amdgcn_global_load_lds((const __attribute__((address_space(1))) u32*)ga,
                                       (__attribute__((address_space(3))) u32*)&As[lbase],
                                       16, 0, 0);
      const f16* gb = BT + (size_t)(n0 + r) * ldb + k0 + c8;
      __builtin_amdgcn_global_load_lds((const __attribute__((address_space(1))) u32*)gb,
                                       (__attribute__((address_space(3))) u32*)&Bs[lbase],
                                       16, 0, 0);
    }
    __syncthreads();
    #pragma unroll
    for (int ks = 0; ks < 2; ++ks) {
      f16x8 af[4], bfr[4];
      #pragma unroll
      for (int m = 0; m < 4; ++m)
        af[m] = *(const f16x8*)&As[(wr + m * 16 + lrow) * 64 + ks * 32 + kgrp];
      #pragma unroll
      for (int n = 0; n < 4; ++n)
        bfr[n] = *(const f16x8*)&Bs[(wc + n * 16 + lrow) * 64 + ks * 32 + kgrp];
      #pragma unroll
      for (int m = 0; m < 4; ++m)
        #pragma unroll
        for (int n = 0; n < 4; ++n)
          acc[m][n] = __builtin_amdgcn_mfma_f32_16x16x32_f16(af[m], bfr[n], acc[m][n], 0, 0, 0);
    }
  }
  const int rbase = m0 + wr + (lane >> 4) * 4;  // C/D: col=lane&15, row=(lane>>4)*4+reg [m89]
  #pragma unroll
  for (int n = 0; n < 4; ++n) {
    int col = n0 + wc + n * 16 + lrow;
    float bv = bias ? bias[col] : 0.0f;
    #pragma unroll
    for (int m = 0; m < 4; ++m) {
      #pragma unroll
      for (int j = 0; j < 4; ++j) {
        int rowi = rbase + m * 16 + j;
        float v = acc[m][n][j] + bv;
        if (OUTF16) Ch[(size_t)rowi * ldc + col] = (f16)v;
        else        C[(size_t)rowi * ldc + col] = v;
      }
    }
  }
}

// ------------------------------------------------------------- RoPE tables
__global__ void k_rope_table(float* __restrict__ rc, float* __restrict__ rs)
{
  int t = blockIdx.x, i = threadIdx.x;  // 2048 x 64
  int fi = (2 * i) & 63;
  double inv = pow(10000.0, -(double)fi / 64.0);
  double a = (double)t * inv;
  rc[t * 64 + i] = (float)cos(a);
  rs[t * 64 + i] = (float)sin(a);
}

__global__ __launch_bounds__(256) void k_rope_q(const f16* __restrict__ q,
                                                const float* __restrict__ rc,
                                                const float* __restrict__ rs,
                                                f16* __restrict__ out)
{
  int g = blockIdx.x * 256 + threadIdx.x;  // 4096*16*64
  int row = g >> 10, rem = g & 1023;
  int h = rem >> 6, i = rem & 63;
  int t = row & 2047;
  size_t base = (size_t)row * 2048 + h * 128 + 2 * i;
  f16x2 v = *(const f16x2*)&q[base];
  float x1 = (float)v.x, x2 = (float)v.y;
  float c = rc[t * 64 + i], s = rs[t * 64 + i];
  f16x2 o; o.x = (f16)(x1 * c - x2 * s); o.y = (f16)(x1 * s + x2 * c);
  *(f16x2*)&out[base] = o;
}

__global__ __launch_bounds__(256) void k_rope_kv(const f16* __restrict__ kv,
                                                 const float* __restrict__ rc,
                                                 const float* __restrict__ rs,
                                                 f16* __restrict__ kout, f16* __restrict__ vout)
{
  int g = blockIdx.x * 256 + threadIdx.x;  // 4096*4*64
  int row = g >> 8, rem = g & 255;
  int kvh = rem >> 6, i = rem & 63;
  int t = row & 2047;
  size_t kb = (size_t)row * 1024 + kvh * 128 + 2 * i;
  f16x2 kvp = *(const f16x2*)&kv[kb];
  float x1 = (float)kvp.x, x2 = (float)kvp.y;
  float c = rc[t * 64 + i], s = rs[t * 64 + i];
  size_t ob = (size_t)row * 512 + kvh * 128 + 2 * i;
  f16x2 ko; ko.x = (f16)(x1 * c - x2 * s); ko.y = (f16)(x1 * s + x2 * c);
  *(f16x2*)&kout[ob] = ko;
  f16x2 vp = *(const f16x2*)&kv[(size_t)row * 1024 + 512 + kvh * 128 + 2 * i];
  *(f16x2*)&vout[ob] = vp;
}

// ------------------------------------------------------------- exact top-64, fp64 scores
// 2 rows/block; COALESCED score phase via ksT [2][64][2048] (lane = key index);
// su storage XOR-swizzled (suX) to kill the tid*8 sweep bank conflicts.
// Select/resolve/emit: R5's deterministic structure per row (proven on-device).
__global__ __launch_bounds__(256) void k_topk64(const double* __restrict__ qs,
                                                const double* __restrict__ ksT,
                                                int* __restrict__ selcnt,
                                                int* __restrict__ selidx)
{
  const int r0 = blockIdx.x * 2;
  const int b = r0 >> 11;
  const int t0 = r0 & 2047, t1 = t0 + 1;
  const int tid = threadIdx.x;
  if (t1 < 64) {  // both rows trivial (t0 even => covers exactly rows 0..63)
    for (int lr = 0; lr < 2; ++lr) {
      int t = t0 + lr;
      int* outp = selidx + (size_t)(r0 + lr) * 68;
      for (int jj = tid; jj <= t; jj += 256) outp[jj] = jj;
      if (tid == 0) selcnt[r0 + lr] = t + 1;
    }
    return;
  }
  __shared__ double qrowP[64][2];
  __shared__ u64 su[2][2048];
  __shared__ unsigned hist[256], sA[256], sB[256];
  __shared__ unsigned s_bsel, s_larger, s_cnt;
  __shared__ u64 s_thr;
  __shared__ int s_remfin;
  __shared__ int cand[128];
  __shared__ u64 ckey[128];

  if (tid < 128) qrowP[tid >> 1][tid & 1] = qs[(size_t)(r0 + (tid & 1)) * 64 + (tid >> 1)];
  __syncthreads();
  // ---- scores: lane = key, coalesced 8B loads; one ksT read feeds both rows ----
  {
    const double* kb = ksT + (size_t)b * 64 * 2048;
    const int emax = t1 >> 8;  // block-uniform
    for (int e = 0; e <= emax; ++e) {
      const int jj = e * 256 + tid;
      double acc0 = 0.0, acc1 = 0.0;
      const double* kp = kb + jj;
      #pragma unroll 16
      for (int d = 0; d < 64; ++d) {
        double kv = kp[(size_t)d * 2048];
        f64x2 qp = *(const f64x2*)&qrowP[d][0];  // LDS broadcast
        acc0 = fma(qp.x, kv, acc0);
        acc1 = fma(qp.y, kv, acc1);
      }
      const int sx = suX(jj);
      u64 u0 = (u64)__double_as_longlong(acc0);
      su[0][sx] = (u0 >> 63) ? ~u0 : (u0 | 0x8000000000000000ull);
      u64 u1 = (u64)__double_as_longlong(acc1);
      su[1][sx] = (u1 >> 63) ? ~u1 : (u1 | 0x8000000000000000ull);
    }
  }
  __syncthreads();

  const int c0 = tid * 8;
  for (int lr = 0; lr < 2; ++lr) {
    const int t = t0 + lr;
    int* outp = selidx + (size_t)(r0 + lr) * 68;
    const u64* S = su[lr];
    // ---- radix select with early exit ----
    u64 prefix = 0;
    int remaining = 64;
    int broke = 0, sh_final = 0;
    for (int byte = 7; byte >= 0; --byte) {
      const int sh = byte * 8;
      hist[tid] = 0;
      __syncthreads();
      {
        unsigned bn[8]; bool vl[8];
        #pragma unroll
        for (int e = 0; e < 8; ++e) {
          int jj = c0 + e;
          u64 u = (jj <= t) ? S[suX(jj)] : 0;
          bool ok = (jj <= t) && ((byte == 7) || (((u ^ prefix) >> (sh + 8)) == 0));
          bn[e] = (unsigned)((u >> sh) & 255);
          vl[e] = ok;
        }
        #pragma unroll
        for (int e = 0; e < 8; ++e) {
          if (vl[e]) {
            bool first = true;
            #pragma unroll
            for (int p = 0; p < 8; ++p)
              if (p < e && vl[p] && bn[p] == bn[e]) first = false;
            if (first) {
              unsigned c = 0;
              #pragma unroll
              for (int q = 0; q < 8; ++q)
                if (q >= e && vl[q] && bn[q] == bn[e]) ++c;
              atomicAdd(&hist[bn[e]], c);
            }
          }
        }
      }
      __syncthreads();
      unsigned* sp = sA; unsigned* dp = sB;
      sp[tid] = hist[tid];
      __syncthreads();
      #pragma unroll
      for (int off = 1; off < 256; off <<= 1) {
        dp[tid] = sp[tid] + ((tid + off < 256) ? sp[tid + off] : 0u);
        __syncthreads();
        unsigned* tpp = sp; sp = dp; dp = tpp;
      }
      unsigned inc = sp[tid];
      unsigned cumAbove = (tid == 255) ? 0u : sp[tid + 1];
      if ((int)cumAbove < remaining && (int)inc >= remaining) {
        s_bsel = (unsigned)tid;
        s_larger = cumAbove;
        s_cnt = inc - cumAbove;
      }
      __syncthreads();
      prefix |= ((u64)s_bsel << sh);
      remaining -= (int)s_larger;
      int cnt = (int)s_cnt;
      __syncthreads();
      if (cnt <= 128) { broke = 1; sh_final = sh; break; }
    }
    // ---- resolve exact 64th-largest among candidates ----
    u64 thr;
    int remfin;
    if (broke) {
      unsigned cg = 0;
      #pragma unroll
      for (int e = 0; e < 8; ++e) {
        int jj = c0 + e;
        if (jj <= t && (((S[suX(jj)] ^ prefix) >> sh_final) == 0)) ++cg;
      }
      unsigned* sp = sA; unsigned* dp = sB;
      sp[tid] = cg;
      __syncthreads();
      #pragma unroll
      for (int off = 1; off < 256; off <<= 1) {
        dp[tid] = sp[tid] + ((tid >= off) ? sp[tid - off] : 0u);
        __syncthreads();
        unsigned* tpp = sp; sp = dp; dp = tpp;
      }
      const int C = (int)sp[255];
      int pos = (int)(sp[tid] - cg);
      #pragma unroll
      for (int e = 0; e < 8; ++e) {
        int jj = c0 + e;
        if (jj <= t && (((S[suX(jj)] ^ prefix) >> sh_final) == 0)) cand[pos++] = jj;
      }
      __syncthreads();
      if (tid < C) ckey[tid] = S[suX(cand[tid])];
      __syncthreads();
      if (tid < C) {
        u64 k = ckey[tid];
        int g = 0, eq = 0;
        for (int j = 0; j < C; ++j) {
          g += (ckey[j] > k) ? 1 : 0;
          eq += (ckey[j] == k) ? 1 : 0;
        }
        if (g < remaining && remaining <= g + eq) {
          s_thr = k;
          s_remfin = remaining - g;
        }
      }
      __syncthreads();
      thr = s_thr;
      remfin = s_remfin;
    } else {
      thr = prefix;
      remfin = remaining;
    }
    __syncthreads();
    // ---- deterministic emit: diag, greaters asc, first remfin ties asc ----
    unsigned cg = 0, ct_ = 0;
    #pragma unroll
    for (int e = 0; e < 8; ++e) {
      int jj = c0 + e;
      if (jj <= t) {
        u64 u = S[suX(jj)];
        cg += (u > thr) ? 1u : 0u;
        ct_ += (u == thr) ? 1u : 0u;
      }
    }
    const unsigned pack = cg | (ct_ << 16);
    {
      unsigned* sp = sA; unsigned* dp = sB;
      sp[tid] = pack;
      __syncthreads();
      #pragma unroll
      for (int off = 1; off < 256; off <<= 1) {
        dp[tid] = sp[tid] + ((tid >= off) ? sp[tid - off] : 0u);
        __syncthreads();
        unsigned* tpp = sp; sp = dp; dp = tpp;
      }
      const unsigned excl = sp[tid] - pack;
      const unsigned tot = sp[255];
      const unsigned Gtot = tot & 0xFFFFu;
      const u64 ut = S[suX(t)];
      const unsigned gt = (ut > thr) ? 1u : 0u;
      const unsigned tt = (ut == thr) ? 1u : 0u;
      const int GtotX = (int)(Gtot - gt);
      int gpos = (int)(excl & 0xFFFFu);
      int tpos = (int)(excl >> 16);
      #pragma unroll
      for (int e = 0; e < 8; ++e) {
        int jj = c0 + e;
        if (jj > t) break;
        u64 u = S[suX(jj)];
        if (u > thr) {
          if (jj != t) outp[1 + gpos] = jj;
          ++gpos;
        } else if (u == thr) {
          if (jj != t && tpos < remfin) outp[1 + GtotX + tpos] = jj;
          ++tpos;
        }
      }
      if (tid == 0) {
        outp[0] = t;
        const unsigned Ttot = tot >> 16;
        int tb = (int)(Ttot - tt);
        int emitT = tb < remfin ? tb : remfin;
        selcnt[r0 + lr] = 1 + GtotX + emitT;  // 64 or 65
      }
    }
    __syncthreads();
  }
}

// ------------------------------------------------------------- sparse attention
__global__ __launch_bounds__(256) void k_attn(const f16* __restrict__ qr,
                                              const f16* __restrict__ kr,
                                              const f16* __restrict__ vv,
                                              const int* __restrict__ selcnt,
                                              const int* __restrict__ selidx,
                                              f16* __restrict__ y)
{
  const int blk = blockIdx.x;  // row*4 + kvh
  const int row = blk >> 2, kvh = blk & 3;
  const int b = row >> 11;
  const int tid = threadIdx.x, lane = tid & 63, wave = tid >> 6;
  const int cnt = selcnt[row];
  __shared__ int sidx[68];
  __shared__ f16 qlds[4][128];
  __shared__ float pl[4][66];
  if (tid < cnt) sidx[tid] = selidx[(size_t)row * 68 + tid];
  *(f16x2*)&qlds[wave][lane * 2] =
      *(const f16x2*)&qr[((size_t)row * 16 + kvh * 4 + wave) * 128 + lane * 2];
  __syncthreads();

  const float SCALE = 0.08838834764831845f;  // 1/sqrt(128)
  auto dotk = [&](int key) -> float {
    const f16* kp = &kr[((size_t)(b * 2048 + key)) * 512 + kvh * 128];
    float s = 0.0f;
    #pragma unroll
    for (int i = 0; i < 16; ++i) {
      f16x8 k8 = *(const f16x8*)&kp[i * 8];
      f16x8 q8 = *(const f16x8*)&qlds[wave][i * 8];
      #pragma unroll
      for (int e = 0; e < 8; ++e) s = fmaf((float)q8[e], (float)k8[e], s);
    }
    return s * SCALE;
  };

  float s1 = -__builtin_inff(), s2 = -__builtin_inff();
  if (lane < cnt) s1 = dotk(sidx[lane]);
  if (lane + 64 < cnt) s2 = dotk(sidx[lane + 64]);  // only lane 0, cnt==65
  float mx = fmaxf(s1, s2);
  #pragma unroll
  for (int off = 32; off; off >>= 1) mx = fmaxf(mx, __shfl_xor(mx, off));
  float p1 = (lane < cnt) ? __expf(s1 - mx) : 0.0f;
  float p2 = (lane + 64 < cnt) ? __expf(s2 - mx) : 0.0f;
  float l = p1 + p2;
  #pragma unroll
  for (int off = 32; off; off >>= 1) l += __shfl_xor(l, off);
  float linv = 1.0f / l;
  pl[wave][lane] = p1;
  if (lane == 0) pl[wave][64] = p2;
  __syncthreads();

  float y0 = 0.0f, y1 = 0.0f;
  const int d2 = lane * 2;
  for (int j = 0; j < cnt; ++j) {
    float p = pl[wave][j];
    int key = sidx[j];
    f16x2 v2 = *(const f16x2*)&vv[((size_t)(b * 2048 + key)) * 512 + kvh * 128 + d2];
    y0 = fmaf(p, (float)v2.x, y0);
    y1 = fmaf(p, (float)v2.y, y1);
  }
  y0 *= linv; y1 *= linv;
  f16x2 o; o.x = (f16)y0; o.y = (f16)y1;
  *(f16x2*)&y[(size_t)row * 2048 + (kvh * 4 + wave) * 128 + d2] = o;
}

// ================================================================ launch
extern "C" void kernel_launch(void* const* d_in, const int* in_sizes, int n_in,
                              void* d_out, int out_size, void* d_ws, size_t ws_size,
                              hipStream_t stream)
{
  (void)in_sizes; (void)n_in; (void)out_size; (void)ws_size;
  const float* x   = (const float*)d_in[0];
  const float* Wq  = (const float*)d_in[1];
  const float* bq  = (const float*)d_in[2];
  const float* Wkd = (const float*)d_in[3];
  const float* bkd = (const float*)d_in[4];
  const float* Wku = (const float*)d_in[5];
  const float* bku = (const float*)d_in[6];
  const float* Wo  = (const float*)d_in[7];
  const float* bo  = (const float*)d_in[8];
  float* out = (float*)d_out;

  char* ws = (char*)d_ws;
  size_t o = 0;
  auto alloc = [&](size_t bytes) -> void* {
    o = (o + 255) & ~(size_t)255;
    void* p = ws + o;
    o += bytes;
    return p;
  };
  f16* WqT   = (f16*)alloc(2048ull * 2048 * 2);
  f16* WoT   = (f16*)alloc(2048ull * 2048 * 2);
  f16* WkdT  = (f16*)alloc(512ull * 2048 * 2);
  f16* WkuT  = (f16*)alloc(1024ull * 512 * 2);
  f16* xh    = (f16*)alloc(4096ull * 2048 * 2);
  f16* qmain = (f16*)alloc(4096ull * 2048 * 2);  // reused as y after rope
  f16* kvh_  = (f16*)alloc(4096ull * 1024 * 2);
  f16* cbf   = (f16*)alloc(4096ull * 512 * 2);
  float* rc  = (float*)alloc(2048ull * 64 * 4);
  float* rs  = (float*)alloc(2048ull * 64 * 4);
  f16* qrope = (f16*)alloc(4096ull * 2048 * 2);
  f16* krope = (f16*)alloc(4096ull * 512 * 2);
  f16* vbf   = (f16*)alloc(4096ull * 512 * 2);
  int* selcnt = (int*)alloc(4096ull * 4);
  int* selidx = (int*)alloc(4096ull * 68 * 4);
  double* Bsel = (double*)alloc(2048ull * 128 * 8);
  double* bsel = (double*)alloc(128 * 8);
  double* qs64 = (double*)alloc(4096ull * 64 * 8);
  double* ks64 = (double*)alloc(4096ull * 64 * 8);
  double* ksT  = (double*)alloc(2ull * 64 * 2048 * 8);
  f16* yh = qmain;  // alias: qmain dead after k_rope_q

  // --- weight prep ---
  k_transpose_cast<<<dim3(64, 64), 256, 0, stream>>>(Wq, WqT, 2048, 2048);
  k_transpose_cast<<<dim3(16, 64), 256, 0, stream>>>(Wkd, WkdT, 2048, 512);
  k_transpose_cast<<<dim3(32, 16), 256, 0, stream>>>(Wku, WkuT, 512, 1024);
  k_transpose_cast<<<dim3(64, 64), 256, 0, stream>>>(Wo, WoT, 2048, 2048);
  k_cast_f16<<<8192, 256, 0, stream>>>(x, xh, 2097152);

  // --- fp64 selector path ---
  k_prep_sel<<<2048, 64, 0, stream>>>(Wq, Wkd, Wku, Bsel);
  k_bias_sel<<<1, 128, 0, stream>>>(bq, bkd, Wku, bku, bsel);
  k_gemm_sel_f64<<<dim3(128, 2), 256, 0, stream>>>(x, Bsel, bsel, qs64, ks64);
  k_transpose64<<<dim3(2, 64, 2), 256, 0, stream>>>(ks64, ksT);

  // --- fp16 MFMA main path ---
  k_gemm_bt<true><<<dim3(32, 16), 256, 0, stream>>>(xh, WqT, bq, nullptr, qmain,
                                                    4096, 2048, 2048, 2048, 2048, 2048);
  k_gemm_bt<true><<<dim3(32, 4), 256, 0, stream>>>(xh, WkdT, bkd, nullptr, cbf,
                                                   4096, 512, 2048, 2048, 2048, 512);
  k_gemm_bt<true><<<dim3(32, 8), 256, 0, stream>>>(cbf, WkuT, bku, nullptr, kvh_,
                                                   4096, 1024, 512, 512, 512, 1024);

  // --- RoPE ---
  k_rope_table<<<2048, 64, 0, stream>>>(rc, rs);
  k_rope_q<<<16384, 256, 0, stream>>>(qmain, rc, rs, qrope);
  k_rope_kv<<<4096, 256, 0, stream>>>(kvh_, rc, rs, krope, vbf);

  // --- selector top-k (fp64 exact, coalesced scores, 2 rows/block) ---
  k_topk64<<<2048, 256, 0, stream>>>(qs64, ksT, selcnt, selidx);

  // --- sparse attention ---
  k_attn<<<16384, 256, 0, stream>>>(qrope, krope, vbf, selcnt, selidx, yh);

  // --- output projection ---
  k_gemm_bt<false><<<dim3(32, 16), 256, 0, stream>>>(yh, WoT, bo, out, nullptr,
                                                     4096, 2048, 2048, 2048, 2048, 2048);
}

// Round 7
// 546.582 us; speedup vs baseline: 4.5657x; 1.1871x over previous
//
#include <hip/hip_runtime.h>

typedef unsigned int u32;
typedef unsigned long long u64;
typedef _Float16 f16;
typedef __attribute__((ext_vector_type(2))) _Float16 f16x2;
typedef __attribute__((ext_vector_type(4))) _Float16 f16x4;
typedef __attribute__((ext_vector_type(8))) _Float16 f16x8;
typedef __attribute__((ext_vector_type(4))) float f32x4;
typedef __attribute__((ext_vector_type(2))) double f64x2;

// Problem constants: B=2, T=2048, D=2048, LAT=512, H=16, HD=128, NKV=4, G=4,
// SEL_DIM=64, TOPK=64, NROW = 4096

// su storage swizzle: spreads the tid*8+e LDS sweep across 16 banks (bijective
// within each 16-element group: XOR of low-3 bits by bits 4..6).
__device__ __forceinline__ int suX(int jj) { return jj ^ ((jj >> 4) & 7); }

// ------------------------------------------------- transpose + cast f32->f16
// out[C][R] = (f16) in[R][C]
__global__ __launch_bounds__(256) void k_transpose_cast(const float* __restrict__ in,
                                                        f16* __restrict__ out, int R, int C)
{
  __shared__ float tile[32][33];
  int c0 = blockIdx.x * 32, r0 = blockIdx.y * 32;
  int tx = threadIdx.x & 31, ty = threadIdx.x >> 5;  // ty 0..7
  #pragma unroll
  for (int i = ty; i < 32; i += 8) tile[i][tx] = in[(size_t)(r0 + i) * C + c0 + tx];
  __syncthreads();
  #pragma unroll
  for (int i = ty; i < 32; i += 8) out[(size_t)(c0 + i) * R + r0 + tx] = (f16)tile[tx][i];
}

// ------------------------------------------------------------- cast f32->f16
__global__ __launch_bounds__(256) void k_cast_f16(const float* __restrict__ in,
                                                  f16* __restrict__ out, int n4)
{
  int i = blockIdx.x * 256 + threadIdx.x;
  if (i >= n4) return;
  f32x4 v = *(const f32x4*)&in[(size_t)i * 4];
  f16x4 h; h.x = (f16)v.x; h.y = (f16)v.y; h.z = (f16)v.z; h.w = (f16)v.w;
  *(f16x4*)&out[(size_t)i * 4] = h;
}

// ------------------------------------------------------------- fp64 selector weights
__global__ void k_prep_sel(const float* __restrict__ Wq, const float* __restrict__ Wkd,
                           const float* __restrict__ Wku, double* __restrict__ Bsel)
{
  const int k = blockIdx.x;   // 0..2047
  const int j = threadIdx.x;  // 0..63
  Bsel[(size_t)k * 128 + j] = (double)Wq[(size_t)k * 2048 + j];
  double s = 0.0;
  for (int l = 0; l < 512; ++l)
    s = fma((double)Wkd[(size_t)k * 512 + l], (double)Wku[(size_t)l * 1024 + j], s);
  Bsel[(size_t)k * 128 + 64 + j] = s;
}

__global__ void k_bias_sel(const float* __restrict__ bq, const float* __restrict__ bkd,
                           const float* __restrict__ Wku, const float* __restrict__ bku,
                           double* __restrict__ bsel)
{
  int j = threadIdx.x;  // 0..127
  if (j < 64) {
    bsel[j] = (double)bq[j];
  } else {
    int jj = j - 64;
    double s = (double)bku[jj];
    for (int l = 0; l < 512; ++l)
      s = fma((double)bkd[l], (double)Wku[(size_t)l * 1024 + jj], s);
    bsel[j] = s;
  }
}

// ------------------------------------------------------------- fp64 selector GEMM
__global__ __launch_bounds__(256) void k_gemm_sel_f64(const float* __restrict__ A,
                                                      const double* __restrict__ Bsel,
                                                      const double* __restrict__ bias,
                                                      double* __restrict__ qs64,
                                                      double* __restrict__ ks64)
{
  __shared__ double As[32][33];
  __shared__ double Bs[32][66];
  const int m0 = blockIdx.x * 32, n0 = blockIdx.y * 64;
  const int tid = threadIdx.x;
  const int tx = tid & 15, ty = tid >> 4;
  const int ar = tid >> 3, ac4 = (tid & 7) * 4;
  double acc[2][4] = {};

  f32x4 aN = *(const f32x4*)&A[(size_t)(m0 + ar) * 2048 + ac4];
  f64x2 bN[4];
  #pragma unroll
  for (int it = 0; it < 4; ++it) {
    int c = it * 256 + tid; int kk = c >> 5, n2 = (c & 31) * 2;
    bN[it] = *(const f64x2*)&Bsel[(size_t)kk * 128 + n0 + n2];
  }
  for (int k0 = 0; k0 < 2048; k0 += 32) {
    __syncthreads();
    As[ar][ac4] = (double)aN.x; As[ar][ac4 + 1] = (double)aN.y;
    As[ar][ac4 + 2] = (double)aN.z; As[ar][ac4 + 3] = (double)aN.w;
    #pragma unroll
    for (int it = 0; it < 4; ++it) {
      int c = it * 256 + tid; int kk = c >> 5, n2 = (c & 31) * 2;
      Bs[kk][n2] = bN[it].x; Bs[kk][n2 + 1] = bN[it].y;
    }
    __syncthreads();
    if (k0 + 32 < 2048) {
      aN = *(const f32x4*)&A[(size_t)(m0 + ar) * 2048 + k0 + 32 + ac4];
      #pragma unroll
      for (int it = 0; it < 4; ++it) {
        int c = it * 256 + tid; int kk = c >> 5, n2 = (c & 31) * 2;
        bN[it] = *(const f64x2*)&Bsel[(size_t)(k0 + 32 + kk) * 128 + n0 + n2];
      }
    }
    #pragma unroll
    for (int kk = 0; kk < 32; ++kk) {
      double a0 = As[ty * 2][kk], a1 = As[ty * 2 + 1][kk];
      f64x2 b01 = *(const f64x2*)&Bs[kk][tx * 4];
      f64x2 b23 = *(const f64x2*)&Bs[kk][tx * 4 + 2];
      acc[0][0] = fma(a0, b01.x, acc[0][0]); acc[0][1] = fma(a0, b01.y, acc[0][1]);
      acc[0][2] = fma(a0, b23.x, acc[0][2]); acc[0][3] = fma(a0, b23.y, acc[0][3]);
      acc[1][0] = fma(a1, b01.x, acc[1][0]); acc[1][1] = fma(a1, b01.y, acc[1][1]);
      acc[1][2] = fma(a1, b23.x, acc[1][2]); acc[1][3] = fma(a1, b23.y, acc[1][3]);
    }
  }
  #pragma unroll
  for (int i = 0; i < 2; ++i) {
    int row = m0 + ty * 2 + i;
    #pragma unroll
    for (int j = 0; j < 4; ++j) {
      int n = n0 + tx * 4 + j;
      double v = acc[i][j] + bias[n];
      if (n < 64) qs64[(size_t)row * 64 + n] = v;
      else        ks64[(size_t)row * 64 + (n - 64)] = v;
    }
  }
}

// ------------------------------------------------------------- fp64 transpose
// ks64 [2][2048][64] -> ksT [2][64][2048]
__global__ __launch_bounds__(256) void k_transpose64(const double* __restrict__ in,
                                                     double* __restrict__ out)
{
  __shared__ double tile[32][33];
  const int bt = blockIdx.z;
  const int c0 = blockIdx.x * 32;
  const int r0 = blockIdx.y * 32;
  int tx = threadIdx.x & 31, ty = threadIdx.x >> 5;
  const double* ip = in + (size_t)bt * 2048 * 64;
  double* op = out + (size_t)bt * 64 * 2048;
  #pragma unroll
  for (int i = ty; i < 32; i += 8) tile[i][tx] = ip[(size_t)(r0 + i) * 64 + c0 + tx];
  __syncthreads();
  #pragma unroll
  for (int i = ty; i < 32; i += 8) op[(size_t)(c0 + i) * 2048 + r0 + tx] = tile[tx][i];
}

// ------------------------------------------------------------- fp16 MFMA GEMM (m97 structure)
template <bool OUTF16>
__global__ __launch_bounds__(256) void k_gemm_bt(const f16* __restrict__ A,
                                                 const f16* __restrict__ BT,
                                                 const float* __restrict__ bias,
                                                 float* __restrict__ C, f16* __restrict__ Ch,
                                                 int M, int N, int K, int lda, int ldb, int ldc)
{
  __shared__ __align__(16) f16 As[128 * 64];
  __shared__ __align__(16) f16 Bs[128 * 64];
  const int tid = threadIdx.x;
  const int lane = tid & 63;
  const int wave = tid >> 6;
  const int m0 = blockIdx.x * 128, n0 = blockIdx.y * 128;
  const int wr = (wave >> 1) * 64, wc = (wave & 1) * 64;
  const int lrow = lane & 15;
  const int kgrp = (lane >> 4) * 8;
  f32x4 acc[4][4] = {};

  for (int k0 = 0; k0 < K; k0 += 64) {
    __syncthreads();
    #pragma unroll
    for (int it = 0; it < 4; ++it) {
      int c = it * 256 + tid;
      int r = c >> 3, c8 = (c & 7) * 8;
      int lbase = (it * 256 + (tid & 192)) * 8;  // wave-uniform LDS offset
      const f16* ga = A + (size_t)(m0 + r) * lda + k0 + c8;
      __builtin_amdgcn_global_load_lds((const __attribute__((address_space(1))) u32*)ga,
                                       (__attribute__((address_space(3))) u32*)&As[lbase],
                                       16, 0, 0);
      const f16* gb = BT + (size_t)(n0 + r) * ldb + k0 + c8;
      __builtin_amdgcn_global_load_lds((const __attribute__((address_space(1))) u32*)gb,
                                       (__attribute__((address_space(3))) u32*)&Bs[lbase],
                                       16, 0, 0);
    }
    __syncthreads();
    #pragma unroll
    for (int ks = 0; ks < 2; ++ks) {
      f16x8 af[4], bfr[4];
      #pragma unroll
      for (int m = 0; m < 4; ++m)
        af[m] = *(const f16x8*)&As[(wr + m * 16 + lrow) * 64 + ks * 32 + kgrp];
      #pragma unroll
      for (int n = 0; n < 4; ++n)
        bfr[n] = *(const f16x8*)&Bs[(wc + n * 16 + lrow) * 64 + ks * 32 + kgrp];
      #pragma unroll
      for (int m = 0; m < 4; ++m)
        #pragma unroll
        for (int n = 0; n < 4; ++n)
          acc[m][n] = __builtin_amdgcn_mfma_f32_16x16x32_f16(af[m], bfr[n], acc[m][n], 0, 0, 0);
    }
  }
  const int rbase = m0 + wr + (lane >> 4) * 4;  // C/D: col=lane&15, row=(lane>>4)*4+reg [m89]
  #pragma unroll
  for (int n = 0; n < 4; ++n) {
    int col = n0 + wc + n * 16 + lrow;
    float bv = bias ? bias[col] : 0.0f;
    #pragma unroll
    for (int m = 0; m < 4; ++m) {
      #pragma unroll
      for (int j = 0; j < 4; ++j) {
        int rowi = rbase + m * 16 + j;
        float v = acc[m][n][j] + bv;
        if (OUTF16) Ch[(size_t)rowi * ldc + col] = (f16)v;
        else        C[(size_t)rowi * ldc + col] = v;
      }
    }
  }
}

// ------------------------------------------------------------- RoPE tables
__global__ void k_rope_table(float* __restrict__ rc, float* __restrict__ rs)
{
  int t = blockIdx.x, i = threadIdx.x;  // 2048 x 64
  int fi = (2 * i) & 63;
  double inv = pow(10000.0, -(double)fi / 64.0);
  double a = (double)t * inv;
  rc[t * 64 + i] = (float)cos(a);
  rs[t * 64 + i] = (float)sin(a);
}

__global__ __launch_bounds__(256) void k_rope_q(const f16* __restrict__ q,
                                                const float* __restrict__ rc,
                                                const float* __restrict__ rs,
                                                f16* __restrict__ out)
{
  int g = blockIdx.x * 256 + threadIdx.x;  // 4096*16*64
  int row = g >> 10, rem = g & 1023;
  int h = rem >> 6, i = rem & 63;
  int t = row & 2047;
  size_t base = (size_t)row * 2048 + h * 128 + 2 * i;
  f16x2 v = *(const f16x2*)&q[base];
  float x1 = (float)v.x, x2 = (float)v.y;
  float c = rc[t * 64 + i], s = rs[t * 64 + i];
  f16x2 o; o.x = (f16)(x1 * c - x2 * s); o.y = (f16)(x1 * s + x2 * c);
  *(f16x2*)&out[base] = o;
}

__global__ __launch_bounds__(256) void k_rope_kv(const f16* __restrict__ kv,
                                                 const float* __restrict__ rc,
                                                 const float* __restrict__ rs,
                                                 f16* __restrict__ kout, f16* __restrict__ vout)
{
  int g = blockIdx.x * 256 + threadIdx.x;  // 4096*4*64
  int row = g >> 8, rem = g & 255;
  int kvh = rem >> 6, i = rem & 63;
  int t = row & 2047;
  size_t kb = (size_t)row * 1024 + kvh * 128 + 2 * i;
  f16x2 kvp = *(const f16x2*)&kv[kb];
  float x1 = (float)kvp.x, x2 = (float)kvp.y;
  float c = rc[t * 64 + i], s = rs[t * 64 + i];
  size_t ob = (size_t)row * 512 + kvh * 128 + 2 * i;
  f16x2 ko; ko.x = (f16)(x1 * c - x2 * s); ko.y = (f16)(x1 * s + x2 * c);
  *(f16x2*)&kout[ob] = ko;
  f16x2 vp = *(const f16x2*)&kv[(size_t)row * 1024 + 512 + kvh * 128 + 2 * i];
  *(f16x2*)&vout[ob] = vp;
}

// ------------------------------------------------------------- exact top-64, fp64 scores
// 2 rows/block; coalesced score phase via ksT; deterministic select (R5/R6 proven).
__global__ __launch_bounds__(256) void k_topk64(const double* __restrict__ qs,
                                                const double* __restrict__ ksT,
                                                int* __restrict__ selcnt,
                                                int* __restrict__ selidx)
{
  const int r0 = blockIdx.x * 2;
  const int b = r0 >> 11;
  const int t0 = r0 & 2047, t1 = t0 + 1;
  const int tid = threadIdx.x;
  if (t1 < 64) {
    for (int lr = 0; lr < 2; ++lr) {
      int t = t0 + lr;
      int* outp = selidx + (size_t)(r0 + lr) * 68;
      for (int jj = tid; jj <= t; jj += 256) outp[jj] = jj;
      if (tid == 0) selcnt[r0 + lr] = t + 1;
    }
    return;
  }
  __shared__ double qrowP[64][2];
  __shared__ u64 su[2][2048];
  __shared__ unsigned hist[256], sA[256], sB[256];
  __shared__ unsigned s_bsel, s_larger, s_cnt;
  __shared__ u64 s_thr;
  __shared__ int s_remfin;
  __shared__ int cand[128];
  __shared__ u64 ckey[128];

  if (tid < 128) qrowP[tid >> 1][tid & 1] = qs[(size_t)(r0 + (tid & 1)) * 64 + (tid >> 1)];
  __syncthreads();
  {
    const double* kb = ksT + (size_t)b * 64 * 2048;
    const int emax = t1 >> 8;
    for (int e = 0; e <= emax; ++e) {
      const int jj = e * 256 + tid;
      double acc0 = 0.0, acc1 = 0.0;
      const double* kp = kb + jj;
      #pragma unroll 16
      for (int d = 0; d < 64; ++d) {
        double kv = kp[(size_t)d * 2048];
        f64x2 qp = *(const f64x2*)&qrowP[d][0];
        acc0 = fma(qp.x, kv, acc0);
        acc1 = fma(qp.y, kv, acc1);
      }
      const int sx = suX(jj);
      u64 u0 = (u64)__double_as_longlong(acc0);
      su[0][sx] = (u0 >> 63) ? ~u0 : (u0 | 0x8000000000000000ull);
      u64 u1 = (u64)__double_as_longlong(acc1);
      su[1][sx] = (u1 >> 63) ? ~u1 : (u1 | 0x8000000000000000ull);
    }
  }
  __syncthreads();

  const int c0 = tid * 8;
  for (int lr = 0; lr < 2; ++lr) {
    const int t = t0 + lr;
    int* outp = selidx + (size_t)(r0 + lr) * 68;
    const u64* S = su[lr];
    u64 prefix = 0;
    int remaining = 64;
    int broke = 0, sh_final = 0;
    for (int byte = 7; byte >= 0; --byte) {
      const int sh = byte * 8;
      hist[tid] = 0;
      __syncthreads();
      {
        unsigned bn[8]; bool vl[8];
        #pragma unroll
        for (int e = 0; e < 8; ++e) {
          int jj = c0 + e;
          u64 u = (jj <= t) ? S[suX(jj)] : 0;
          bool ok = (jj <= t) && ((byte == 7) || (((u ^ prefix) >> (sh + 8)) == 0));
          bn[e] = (unsigned)((u >> sh) & 255);
          vl[e] = ok;
        }
        #pragma unroll
        for (int e = 0; e < 8; ++e) {
          if (vl[e]) {
            bool first = true;
            #pragma unroll
            for (int p = 0; p < 8; ++p)
              if (p < e && vl[p] && bn[p] == bn[e]) first = false;
            if (first) {
              unsigned c = 0;
              #pragma unroll
              for (int q = 0; q < 8; ++q)
                if (q >= e && vl[q] && bn[q] == bn[e]) ++c;
              atomicAdd(&hist[bn[e]], c);
            }
          }
        }
      }
      __syncthreads();
      unsigned* sp = sA; unsigned* dp = sB;
      sp[tid] = hist[tid];
      __syncthreads();
      #pragma unroll
      for (int off = 1; off < 256; off <<= 1) {
        dp[tid] = sp[tid] + ((tid + off < 256) ? sp[tid + off] : 0u);
        __syncthreads();
        unsigned* tpp = sp; sp = dp; dp = tpp;
      }
      unsigned inc = sp[tid];
      unsigned cumAbove = (tid == 255) ? 0u : sp[tid + 1];
      if ((int)cumAbove < remaining && (int)inc >= remaining) {
        s_bsel = (unsigned)tid;
        s_larger = cumAbove;
        s_cnt = inc - cumAbove;
      }
      __syncthreads();
      prefix |= ((u64)s_bsel << sh);
      remaining -= (int)s_larger;
      int cnt = (int)s_cnt;
      __syncthreads();
      if (cnt <= 128) { broke = 1; sh_final = sh; break; }
    }
    u64 thr;
    int remfin;
    if (broke) {
      unsigned cg = 0;
      #pragma unroll
      for (int e = 0; e < 8; ++e) {
        int jj = c0 + e;
        if (jj <= t && (((S[suX(jj)] ^ prefix) >> sh_final) == 0)) ++cg;
      }
      unsigned* sp = sA; unsigned* dp = sB;
      sp[tid] = cg;
      __syncthreads();
      #pragma unroll
      for (int off = 1; off < 256; off <<= 1) {
        dp[tid] = sp[tid] + ((tid >= off) ? sp[tid - off] : 0u);
        __syncthreads();
        unsigned* tpp = sp; sp = dp; dp = tpp;
      }
      const int C = (int)sp[255];
      int pos = (int)(sp[tid] - cg);
      #pragma unroll
      for (int e = 0; e < 8; ++e) {
        int jj = c0 + e;
        if (jj <= t && (((S[suX(jj)] ^ prefix) >> sh_final) == 0)) cand[pos++] = jj;
      }
      __syncthreads();
      if (tid < C) ckey[tid] = S[suX(cand[tid])];
      __syncthreads();
      if (tid < C) {
        u64 k = ckey[tid];
        int g = 0, eq = 0;
        for (int j = 0; j < C; ++j) {
          g += (ckey[j] > k) ? 1 : 0;
          eq += (ckey[j] == k) ? 1 : 0;
        }
        if (g < remaining && remaining <= g + eq) {
          s_thr = k;
          s_remfin = remaining - g;
        }
      }
      __syncthreads();
      thr = s_thr;
      remfin = s_remfin;
    } else {
      thr = prefix;
      remfin = remaining;
    }
    __syncthreads();
    unsigned cg = 0, ct_ = 0;
    #pragma unroll
    for (int e = 0; e < 8; ++e) {
      int jj = c0 + e;
      if (jj <= t) {
        u64 u = S[suX(jj)];
        cg += (u > thr) ? 1u : 0u;
        ct_ += (u == thr) ? 1u : 0u;
      }
    }
    const unsigned pack = cg | (ct_ << 16);
    {
      unsigned* sp = sA; unsigned* dp = sB;
      sp[tid] = pack;
      __syncthreads();
      #pragma unroll
      for (int off = 1; off < 256; off <<= 1) {
        dp[tid] = sp[tid] + ((tid >= off) ? sp[tid - off] : 0u);
        __syncthreads();
        unsigned* tpp = sp; sp = dp; dp = tpp;
      }
      const unsigned excl = sp[tid] - pack;
      const unsigned tot = sp[255];
      const unsigned Gtot = tot & 0xFFFFu;
      const u64 ut = S[suX(t)];
      const unsigned gt = (ut > thr) ? 1u : 0u;
      const unsigned tt = (ut == thr) ? 1u : 0u;
      const int GtotX = (int)(Gtot - gt);
      int gpos = (int)(excl & 0xFFFFu);
      int tpos = (int)(excl >> 16);
      #pragma unroll
      for (int e = 0; e < 8; ++e) {
        int jj = c0 + e;
        if (jj > t) break;
        u64 u = S[suX(jj)];
        if (u > thr) {
          if (jj != t) outp[1 + gpos] = jj;
          ++gpos;
        } else if (u == thr) {
          if (jj != t && tpos < remfin) outp[1 + GtotX + tpos] = jj;
          ++tpos;
        }
      }
      if (tid == 0) {
        outp[0] = t;
        const unsigned Ttot = tot >> 16;
        int tb = (int)(Ttot - tt);
        int emitT = tb < remfin ? tb : remfin;
        selcnt[r0 + lr] = 1 + GtotX + emitT;  // 64 or 65
      }
    }
    __syncthreads();
  }
}

// ------------------------------------------------------------- sparse attention (v2)
// Block per (row, kvh); 4 waves = 4 q-heads. K/V staged ONCE into LDS by the whole
// block (R6's version had every wave re-gathering the same rows through L1 — the
// 206us was TA line-serialization). K stored chunk-XOR-swizzled so the per-lane-row
// ds_read_b128 hits the 8-lane/bank floor; V linear (lane=dim read is conflict-free).
// QK via v_dot2_f32_f16 (fdot2): 1 instr per 2 f16 products, f32 accum.
__global__ __launch_bounds__(256) void k_attn(const f16* __restrict__ qr,
                                              const f16* __restrict__ kr,
                                              const f16* __restrict__ vv,
                                              const int* __restrict__ selcnt,
                                              const int* __restrict__ selidx,
                                              f16* __restrict__ y)
{
  const int blk = blockIdx.x;  // row*4 + kvh
  const int row = blk >> 2, kvh = blk & 3;
  const int b = row >> 11;
  const int tid = threadIdx.x, lane = tid & 63, wave = tid >> 6;
  const int cnt = selcnt[row];
  __shared__ int sidx[68];
  __shared__ __align__(16) f16 Kl[65 * 128];  // swizzled
  __shared__ __align__(16) f16 Vl[65 * 128];  // linear
  __shared__ f16 qlds[4][128];
  __shared__ float pl[4][66];
  if (tid < cnt) sidx[tid] = selidx[(size_t)row * 68 + tid];
  *(f16x2*)&qlds[wave][lane * 2] =
      *(const f16x2*)&qr[((size_t)row * 16 + kvh * 4 + wave) * 128 + lane * 2];
  __syncthreads();  // sidx ready

  // ---- cooperative K/V staging: cnt rows x 16 chunks of 16B each ----
  const int nch = cnt * 16;
  for (int c = tid; c < nch; c += 256) {
    const int r = c >> 4, ch = c & 15;
    const size_t kbase = ((size_t)(b * 2048 + sidx[r])) * 512 + kvh * 128 + ch * 8;
    f16x8 k8 = *(const f16x8*)&kr[kbase];
    *(f16x8*)&Kl[r * 128 + ((ch ^ (r & 15)) * 8)] = k8;
    f16x8 v8 = *(const f16x8*)&vv[kbase];
    *(f16x8*)&Vl[r * 128 + ch * 8] = v8;
  }
  __syncthreads();

  const float SCALE = 0.08838834764831845f;  // 1/sqrt(128)
  auto dotk = [&](int r) -> float {  // dot(q[wave], K_lds[r]) via fdot2
    const int sw = r & 15;
    float s = 0.0f;
    #pragma unroll
    for (int i = 0; i < 16; ++i) {
      f16x8 k8 = *(const f16x8*)&Kl[r * 128 + ((i ^ sw) * 8)];
      f16x8 q8 = *(const f16x8*)&qlds[wave][i * 8];
      #pragma unroll
      for (int e = 0; e < 4; ++e) {
        f16x2 ka; ka.x = k8[2 * e]; ka.y = k8[2 * e + 1];
        f16x2 qa; qa.x = q8[2 * e]; qa.y = q8[2 * e + 1];
        s = __builtin_amdgcn_fdot2(ka, qa, s, false);
      }
    }
    return s * SCALE;
  };

  float s1 = -__builtin_inff(), s2 = -__builtin_inff();
  if (lane < cnt) s1 = dotk(lane);
  if (lane + 64 < cnt) s2 = dotk(lane + 64);  // only lane 0, cnt==65
  float mx = fmaxf(s1, s2);
  #pragma unroll
  for (int off = 32; off; off >>= 1) mx = fmaxf(mx, __shfl_xor(mx, off));
  float p1 = (lane < cnt) ? __expf(s1 - mx) : 0.0f;
  float p2 = (lane + 64 < cnt) ? __expf(s2 - mx) : 0.0f;
  float l = p1 + p2;
  #pragma unroll
  for (int off = 32; off; off >>= 1) l += __shfl_xor(l, off);
  float linv = 1.0f / l;
  pl[wave][lane] = p1;
  if (lane == 0) pl[wave][64] = p2;
  __syncthreads();

  float y0 = 0.0f, y1 = 0.0f;
  const int d2 = lane * 2;
  for (int j = 0; j < cnt; ++j) {
    float p = pl[wave][j];
    f16x2 v2 = *(const f16x2*)&Vl[j * 128 + d2];
    y0 = fmaf(p, (float)v2.x, y0);
    y1 = fmaf(p, (float)v2.y, y1);
  }
  y0 *= linv; y1 *= linv;
  f16x2 o; o.x = (f16)y0; o.y = (f16)y1;
  *(f16x2*)&y[(size_t)row * 2048 + (kvh * 4 + wave) * 128 + d2] = o;
}

// ================================================================ launch
extern "C" void kernel_launch(void* const* d_in, const int* in_sizes, int n_in,
                              void* d_out, int out_size, void* d_ws, size_t ws_size,
                              hipStream_t stream)
{
  (void)in_sizes; (void)n_in; (void)out_size; (void)ws_size;
  const float* x   = (const float*)d_in[0];
  const float* Wq  = (const float*)d_in[1];
  const float* bq  = (const float*)d_in[2];
  const float* Wkd = (const float*)d_in[3];
  const float* bkd = (const float*)d_in[4];
  const float* Wku = (const float*)d_in[5];
  const float* bku = (const float*)d_in[6];
  const float* Wo  = (const float*)d_in[7];
  const float* bo  = (const float*)d_in[8];
  float* out = (float*)d_out;

  char* ws = (char*)d_ws;
  size_t o = 0;
  auto alloc = [&](size_t bytes) -> void* {
    o = (o + 255) & ~(size_t)255;
    void* p = ws + o;
    o += bytes;
    return p;
  };
  f16* WqT   = (f16*)alloc(2048ull * 2048 * 2);
  f16* WoT   = (f16*)alloc(2048ull * 2048 * 2);
  f16* WkdT  = (f16*)alloc(512ull * 2048 * 2);
  f16* WkuT  = (f16*)alloc(1024ull * 512 * 2);
  f16* xh    = (f16*)alloc(4096ull * 2048 * 2);
  f16* qmain = (f16*)alloc(4096ull * 2048 * 2);  // reused as y after rope
  f16* kvh_  = (f16*)alloc(4096ull * 1024 * 2);
  f16* cbf   = (f16*)alloc(4096ull * 512 * 2);
  float* rc  = (float*)alloc(2048ull * 64 * 4);
  float* rs  = (float*)alloc(2048ull * 64 * 4);
  f16* qrope = (f16*)alloc(4096ull * 2048 * 2);
  f16* krope = (f16*)alloc(4096ull * 512 * 2);
  f16* vbf   = (f16*)alloc(4096ull * 512 * 2);
  int* selcnt = (int*)alloc(4096ull * 4);
  int* selidx = (int*)alloc(4096ull * 68 * 4);
  double* Bsel = (double*)alloc(2048ull * 128 * 8);
  double* bsel = (double*)alloc(128 * 8);
  double* qs64 = (double*)alloc(4096ull * 64 * 8);
  double* ks64 = (double*)alloc(4096ull * 64 * 8);
  double* ksT  = (double*)alloc(2ull * 64 * 2048 * 8);
  f16* yh = qmain;  // alias: qmain dead after k_rope_q

  // --- weight prep ---
  k_transpose_cast<<<dim3(64, 64), 256, 0, stream>>>(Wq, WqT, 2048, 2048);
  k_transpose_cast<<<dim3(16, 64), 256, 0, stream>>>(Wkd, WkdT, 2048, 512);
  k_transpose_cast<<<dim3(32, 16), 256, 0, stream>>>(Wku, WkuT, 512, 1024);
  k_transpose_cast<<<dim3(64, 64), 256, 0, stream>>>(Wo, WoT, 2048, 2048);
  k_cast_f16<<<8192, 256, 0, stream>>>(x, xh, 2097152);

  // --- fp64 selector path ---
  k_prep_sel<<<2048, 64, 0, stream>>>(Wq, Wkd, Wku, Bsel);
  k_bias_sel<<<1, 128, 0, stream>>>(bq, bkd, Wku, bku, bsel);
  k_gemm_sel_f64<<<dim3(128, 2), 256, 0, stream>>>(x, Bsel, bsel, qs64, ks64);
  k_transpose64<<<dim3(2, 64, 2), 256, 0, stream>>>(ks64, ksT);

  // --- fp16 MFMA main path ---
  k_gemm_bt<true><<<dim3(32, 16), 256, 0, stream>>>(xh, WqT, bq, nullptr, qmain,
                                                    4096, 2048, 2048, 2048, 2048, 2048);
  k_gemm_bt<true><<<dim3(32, 4), 256, 0, stream>>>(xh, WkdT, bkd, nullptr, cbf,
                                                   4096, 512, 2048, 2048, 2048, 512);
  k_gemm_bt<true><<<dim3(32, 8), 256, 0, stream>>>(cbf, WkuT, bku, nullptr, kvh_,
                                                   4096, 1024, 512, 512, 512, 1024);

  // --- RoPE ---
  k_rope_table<<<2048, 64, 0, stream>>>(rc, rs);
  k_rope_q<<<16384, 256, 0, stream>>>(qmain, rc, rs, qrope);
  k_rope_kv<<<4096, 256, 0, stream>>>(kvh_, rc, rs, krope, vbf);

  // --- selector top-k ---
  k_topk64<<<2048, 256, 0, stream>>>(qs64, ksT, selcnt, selidx);

  // --- sparse attention (LDS-staged K/V + fdot2) ---
  k_attn<<<16384, 256, 0, stream>>>(qrope, krope, vbf, selcnt, selidx, yh);

  // --- output projection ---
  k_gemm_bt<false><<<dim3(32, 16), 256, 0, stream>>>(yh, WoT, bo, out, nullptr,
                                                     4096, 2048, 2048, 2048, 2048, 2048);
}

// Round 8
// 537.922 us; speedup vs baseline: 4.6392x; 1.0161x over previous
//
#include <hip/hip_runtime.h>

typedef unsigned int u32;
typedef unsigned long long u64;
typedef _Float16 f16;
typedef __attribute__((ext_vector_type(2))) _Float16 f16x2;
typedef __attribute__((ext_vector_type(4))) _Float16 f16x4;
typedef __attribute__((ext_vector_type(8))) _Float16 f16x8;
typedef __attribute__((ext_vector_type(4))) float f32x4;
typedef __attribute__((ext_vector_type(2))) double f64x2;

// Problem constants: B=2, T=2048, D=2048, LAT=512, H=16, HD=128, NKV=4, G=4,
// SEL_DIM=64, TOPK=64, NROW = 4096

// su storage swizzle: spreads the tid*8+e LDS sweep across 16 banks.
__device__ __forceinline__ int suX(int jj) { return jj ^ ((jj >> 4) & 7); }

// ------------------------------------------------- transpose + cast f32->f16
__global__ __launch_bounds__(256) void k_transpose_cast(const float* __restrict__ in,
                                                        f16* __restrict__ out, int R, int C)
{
  __shared__ float tile[32][33];
  int c0 = blockIdx.x * 32, r0 = blockIdx.y * 32;
  int tx = threadIdx.x & 31, ty = threadIdx.x >> 5;  // ty 0..7
  #pragma unroll
  for (int i = ty; i < 32; i += 8) tile[i][tx] = in[(size_t)(r0 + i) * C + c0 + tx];
  __syncthreads();
  #pragma unroll
  for (int i = ty; i < 32; i += 8) out[(size_t)(c0 + i) * R + r0 + tx] = (f16)tile[tx][i];
}

// ------------------------------------------------------------- cast f32->f16
__global__ __launch_bounds__(256) void k_cast_f16(const float* __restrict__ in,
                                                  f16* __restrict__ out, int n4)
{
  int i = blockIdx.x * 256 + threadIdx.x;
  if (i >= n4) return;
  f32x4 v = *(const f32x4*)&in[(size_t)i * 4];
  f16x4 h; h.x = (f16)v.x; h.y = (f16)v.y; h.z = (f16)v.z; h.w = (f16)v.w;
  *(f16x4*)&out[(size_t)i * 4] = h;
}

// ------------------------------------------------------------- fp64 selector weights
__global__ void k_prep_sel(const float* __restrict__ Wq, const float* __restrict__ Wkd,
                           const float* __restrict__ Wku, double* __restrict__ Bsel)
{
  const int k = blockIdx.x;   // 0..2047
  const int j = threadIdx.x;  // 0..63
  Bsel[(size_t)k * 128 + j] = (double)Wq[(size_t)k * 2048 + j];
  double s = 0.0;
  for (int l = 0; l < 512; ++l)
    s = fma((double)Wkd[(size_t)k * 512 + l], (double)Wku[(size_t)l * 1024 + j], s);
  Bsel[(size_t)k * 128 + 64 + j] = s;
}

__global__ void k_bias_sel(const float* __restrict__ bq, const float* __restrict__ bkd,
                           const float* __restrict__ Wku, const float* __restrict__ bku,
                           double* __restrict__ bsel)
{
  int j = threadIdx.x;  // 0..127
  if (j < 64) {
    bsel[j] = (double)bq[j];
  } else {
    int jj = j - 64;
    double s = (double)bku[jj];
    for (int l = 0; l < 512; ++l)
      s = fma((double)bkd[l], (double)Wku[(size_t)l * 1024 + jj], s);
    bsel[j] = s;
  }
}

// ------------------------------------------------------------- fp64 selector GEMM, split-K
// Stage 1: partial[z][4096][128] = x[:, z*512:(z+1)*512] @ Bsel[z*512:(z+1)*512, :]
// (R7 kernel body; R7's 1-block/CU launch was the 119us — 24% VALUBusy at 10.8% occ.)
__global__ __launch_bounds__(256) void k_gemm_sel_f64(const float* __restrict__ A,
                                                      const double* __restrict__ Bsel,
                                                      double* __restrict__ partial)
{
  __shared__ double As[32][33];
  __shared__ double Bs[32][66];
  const int m0 = blockIdx.x * 32, n0 = blockIdx.y * 64;
  const int kbase = blockIdx.z * 512, kend = kbase + 512;
  const int tid = threadIdx.x;
  const int tx = tid & 15, ty = tid >> 4;
  const int ar = tid >> 3, ac4 = (tid & 7) * 4;
  double acc[2][4] = {};

  f32x4 aN = *(const f32x4*)&A[(size_t)(m0 + ar) * 2048 + kbase + ac4];
  f64x2 bN[4];
  #pragma unroll
  for (int it = 0; it < 4; ++it) {
    int c = it * 256 + tid; int kk = c >> 5, n2 = (c & 31) * 2;
    bN[it] = *(const f64x2*)&Bsel[(size_t)(kbase + kk) * 128 + n0 + n2];
  }
  for (int k0 = kbase; k0 < kend; k0 += 32) {
    __syncthreads();
    As[ar][ac4] = (double)aN.x; As[ar][ac4 + 1] = (double)aN.y;
    As[ar][ac4 + 2] = (double)aN.z; As[ar][ac4 + 3] = (double)aN.w;
    #pragma unroll
    for (int it = 0; it < 4; ++it) {
      int c = it * 256 + tid; int kk = c >> 5, n2 = (c & 31) * 2;
      Bs[kk][n2] = bN[it].x; Bs[kk][n2 + 1] = bN[it].y;
    }
    __syncthreads();
    if (k0 + 32 < kend) {
      aN = *(const f32x4*)&A[(size_t)(m0 + ar) * 2048 + k0 + 32 + ac4];
      #pragma unroll
      for (int it = 0; it < 4; ++it) {
        int c = it * 256 + tid; int kk = c >> 5, n2 = (c & 31) * 2;
        bN[it] = *(const f64x2*)&Bsel[(size_t)(k0 + 32 + kk) * 128 + n0 + n2];
      }
    }
    #pragma unroll
    for (int kk = 0; kk < 32; ++kk) {
      double a0 = As[ty * 2][kk], a1 = As[ty * 2 + 1][kk];
      f64x2 b01 = *(const f64x2*)&Bs[kk][tx * 4];
      f64x2 b23 = *(const f64x2*)&Bs[kk][tx * 4 + 2];
      acc[0][0] = fma(a0, b01.x, acc[0][0]); acc[0][1] = fma(a0, b01.y, acc[0][1]);
      acc[0][2] = fma(a0, b23.x, acc[0][2]); acc[0][3] = fma(a0, b23.y, acc[0][3]);
      acc[1][0] = fma(a1, b01.x, acc[1][0]); acc[1][1] = fma(a1, b01.y, acc[1][1]);
      acc[1][2] = fma(a1, b23.x, acc[1][2]); acc[1][3] = fma(a1, b23.y, acc[1][3]);
    }
  }
  double* op = partial + (size_t)blockIdx.z * 4096 * 128;
  #pragma unroll
  for (int i = 0; i < 2; ++i) {
    int row = m0 + ty * 2 + i;
    #pragma unroll
    for (int j = 0; j < 4; ++j) {
      int n = n0 + tx * 4 + j;
      op[(size_t)row * 128 + n] = acc[i][j];
    }
  }
}

// Stage 2: fixed-order reduction of the 4 K-slice partials + bias -> qs64/ks64.
// Deterministic; reassociation error ~1e-16 rel, 8 orders below the min top-k gap.
__global__ __launch_bounds__(256) void k_sel_reduce(const double* __restrict__ partial,
                                                    const double* __restrict__ bias,
                                                    double* __restrict__ qs64,
                                                    double* __restrict__ ks64)
{
  const int idx = blockIdx.x * 256 + threadIdx.x;  // 0 .. 4096*128-1
  const int row = idx >> 7, n = idx & 127;
  const size_t S = 4096 * 128;
  double v = ((partial[idx] + partial[S + idx]) + partial[2 * S + idx]) + partial[3 * S + idx];
  v += bias[n];
  if (n < 64) qs64[(size_t)row * 64 + n] = v;
  else        ks64[(size_t)row * 64 + (n - 64)] = v;
}

// ------------------------------------------------------------- fp64 transpose
// ks64 [2][2048][64] -> ksT [2][64][2048]
__global__ __launch_bounds__(256) void k_transpose64(const double* __restrict__ in,
                                                     double* __restrict__ out)
{
  __shared__ double tile[32][33];
  const int bt = blockIdx.z;
  const int c0 = blockIdx.x * 32;
  const int r0 = blockIdx.y * 32;
  int tx = threadIdx.x & 31, ty = threadIdx.x >> 5;
  const double* ip = in + (size_t)bt * 2048 * 64;
  double* op = out + (size_t)bt * 64 * 2048;
  #pragma unroll
  for (int i = ty; i < 32; i += 8) tile[i][tx] = ip[(size_t)(r0 + i) * 64 + c0 + tx];
  __syncthreads();
  #pragma unroll
  for (int i = ty; i < 32; i += 8) op[(size_t)(c0 + i) * 2048 + r0 + tx] = tile[tx][i];
}

// ------------------------------------------------------------- fp16 MFMA GEMM (m97 structure)
template <bool OUTF16>
__global__ __launch_bounds__(256) void k_gemm_bt(const f16* __restrict__ A,
                                                 const f16* __restrict__ BT,
                                                 const float* __restrict__ bias,
                                                 float* __restrict__ C, f16* __restrict__ Ch,
                                                 int M, int N, int K, int lda, int ldb, int ldc)
{
  __shared__ __align__(16) f16 As[128 * 64];
  __shared__ __align__(16) f16 Bs[128 * 64];
  const int tid = threadIdx.x;
  const int lane = tid & 63;
  const int wave = tid >> 6;
  const int m0 = blockIdx.x * 128, n0 = blockIdx.y * 128;
  const int wr = (wave >> 1) * 64, wc = (wave & 1) * 64;
  const int lrow = lane & 15;
  const int kgrp = (lane >> 4) * 8;
  f32x4 acc[4][4] = {};

  for (int k0 = 0; k0 < K; k0 += 64) {
    __syncthreads();
    #pragma unroll
    for (int it = 0; it < 4; ++it) {
      int c = it * 256 + tid;
      int r = c >> 3, c8 = (c & 7) * 8;
      int lbase = (it * 256 + (tid & 192)) * 8;  // wave-uniform LDS offset
      const f16* ga = A + (size_t)(m0 + r) * lda + k0 + c8;
      __builtin_amdgcn_global_load_lds((const __attribute__((address_space(1))) u32*)ga,
                                       (__attribute__((address_space(3))) u32*)&As[lbase],
                                       16, 0, 0);
      const f16* gb = BT + (size_t)(n0 + r) * ldb + k0 + c8;
      __builtin_amdgcn_global_load_lds((const __attribute__((address_space(1))) u32*)gb,
                                       (__attribute__((address_space(3))) u32*)&Bs[lbase],
                                       16, 0, 0);
    }
    __syncthreads();
    #pragma unroll
    for (int ks = 0; ks < 2; ++ks) {
      f16x8 af[4], bfr[4];
      #pragma unroll
      for (int m = 0; m < 4; ++m)
        af[m] = *(const f16x8*)&As[(wr + m * 16 + lrow) * 64 + ks * 32 + kgrp];
      #pragma unroll
      for (int n = 0; n < 4; ++n)
        bfr[n] = *(const f16x8*)&Bs[(wc + n * 16 + lrow) * 64 + ks * 32 + kgrp];
      #pragma unroll
      for (int m = 0; m < 4; ++m)
        #pragma unroll
        for (int n = 0; n < 4; ++n)
          acc[m][n] = __builtin_amdgcn_mfma_f32_16x16x32_f16(af[m], bfr[n], acc[m][n], 0, 0, 0);
    }
  }
  const int rbase = m0 + wr + (lane >> 4) * 4;  // C/D: col=lane&15, row=(lane>>4)*4+reg [m89]
  #pragma unroll
  for (int n = 0; n < 4; ++n) {
    int col = n0 + wc + n * 16 + lrow;
    float bv = bias ? bias[col] : 0.0f;
    #pragma unroll
    for (int m = 0; m < 4; ++m) {
      #pragma unroll
      for (int j = 0; j < 4; ++j) {
        int rowi = rbase + m * 16 + j;
        float v = acc[m][n][j] + bv;
        if (OUTF16) Ch[(size_t)rowi * ldc + col] = (f16)v;
        else        C[(size_t)rowi * ldc + col] = v;
      }
    }
  }
}

// ------------------------------------------------------------- RoPE tables
__global__ void k_rope_table(float* __restrict__ rc, float* __restrict__ rs)
{
  int t = blockIdx.x, i = threadIdx.x;  // 2048 x 64
  int fi = (2 * i) & 63;
  double inv = pow(10000.0, -(double)fi / 64.0);
  double a = (double)t * inv;
  rc[t * 64 + i] = (float)cos(a);
  rs[t * 64 + i] = (float)sin(a);
}

__global__ __launch_bounds__(256) void k_rope_q(const f16* __restrict__ q,
                                                const float* __restrict__ rc,
                                                const float* __restrict__ rs,
                                                f16* __restrict__ out)
{
  int g = blockIdx.x * 256 + threadIdx.x;  // 4096*16*64
  int row = g >> 10, rem = g & 1023;
  int h = rem >> 6, i = rem & 63;
  int t = row & 2047;
  size_t base = (size_t)row * 2048 + h * 128 + 2 * i;
  f16x2 v = *(const f16x2*)&q[base];
  float x1 = (float)v.x, x2 = (float)v.y;
  float c = rc[t * 64 + i], s = rs[t * 64 + i];
  f16x2 o; o.x = (f16)(x1 * c - x2 * s); o.y = (f16)(x1 * s + x2 * c);
  *(f16x2*)&out[base] = o;
}

__global__ __launch_bounds__(256) void k_rope_kv(const f16* __restrict__ kv,
                                                 const float* __restrict__ rc,
                                                 const float* __restrict__ rs,
                                                 f16* __restrict__ kout, f16* __restrict__ vout)
{
  int g = blockIdx.x * 256 + threadIdx.x;  // 4096*4*64
  int row = g >> 8, rem = g & 255;
  int kvh = rem >> 6, i = rem & 63;
  int t = row & 2047;
  size_t kb = (size_t)row * 1024 + kvh * 128 + 2 * i;
  f16x2 kvp = *(const f16x2*)&kv[kb];
  float x1 = (float)kvp.x, x2 = (float)kvp.y;
  float c = rc[t * 64 + i], s = rs[t * 64 + i];
  size_t ob = (size_t)row * 512 + kvh * 128 + 2 * i;
  f16x2 ko; ko.x = (f16)(x1 * c - x2 * s); ko.y = (f16)(x1 * s + x2 * c);
  *(f16x2*)&kout[ob] = ko;
  f16x2 vp = *(const f16x2*)&kv[(size_t)row * 1024 + 512 + kvh * 128 + 2 * i];
  *(f16x2*)&vout[ob] = vp;
}

// ------------------------------------------------------------- exact top-64, fp64 scores
__global__ __launch_bounds__(256) void k_topk64(const double* __restrict__ qs,
                                                const double* __restrict__ ksT,
                                                int* __restrict__ selcnt,
                                                int* __restrict__ selidx)
{
  const int r0 = blockIdx.x * 2;
  const int b = r0 >> 11;
  const int t0 = r0 & 2047, t1 = t0 + 1;
  const int tid = threadIdx.x;
  if (t1 < 64) {
    for (int lr = 0; lr < 2; ++lr) {
      int t = t0 + lr;
      int* outp = selidx + (size_t)(r0 + lr) * 68;
      for (int jj = tid; jj <= t; jj += 256) outp[jj] = jj;
      if (tid == 0) selcnt[r0 + lr] = t + 1;
    }
    return;
  }
  __shared__ double qrowP[64][2];
  __shared__ u64 su[2][2048];
  __shared__ unsigned hist[256], sA[256], sB[256];
  __shared__ unsigned s_bsel, s_larger, s_cnt;
  __shared__ u64 s_thr;
  __shared__ int s_remfin;
  __shared__ int cand[128];
  __shared__ u64 ckey[128];

  if (tid < 128) qrowP[tid >> 1][tid & 1] = qs[(size_t)(r0 + (tid & 1)) * 64 + (tid >> 1)];
  __syncthreads();
  {
    const double* kb = ksT + (size_t)b * 64 * 2048;
    const int emax = t1 >> 8;
    for (int e = 0; e <= emax; ++e) {
      const int jj = e * 256 + tid;
      double acc0 = 0.0, acc1 = 0.0;
      const double* kp = kb + jj;
      #pragma unroll 16
      for (int d = 0; d < 64; ++d) {
        double kv = kp[(size_t)d * 2048];
        f64x2 qp = *(const f64x2*)&qrowP[d][0];
        acc0 = fma(qp.x, kv, acc0);
        acc1 = fma(qp.y, kv, acc1);
      }
      const int sx = suX(jj);
      u64 u0 = (u64)__double_as_longlong(acc0);
      su[0][sx] = (u0 >> 63) ? ~u0 : (u0 | 0x8000000000000000ull);
      u64 u1 = (u64)__double_as_longlong(acc1);
      su[1][sx] = (u1 >> 63) ? ~u1 : (u1 | 0x8000000000000000ull);
    }
  }
  __syncthreads();

  const int c0 = tid * 8;
  for (int lr = 0; lr < 2; ++lr) {
    const int t = t0 + lr;
    int* outp = selidx + (size_t)(r0 + lr) * 68;
    const u64* S = su[lr];
    u64 prefix = 0;
    int remaining = 64;
    int broke = 0, sh_final = 0;
    for (int byte = 7; byte >= 0; --byte) {
      const int sh = byte * 8;
      hist[tid] = 0;
      __syncthreads();
      {
        unsigned bn[8]; bool vl[8];
        #pragma unroll
        for (int e = 0; e < 8; ++e) {
          int jj = c0 + e;
          u64 u = (jj <= t) ? S[suX(jj)] : 0;
          bool ok = (jj <= t) && ((byte == 7) || (((u ^ prefix) >> (sh + 8)) == 0));
          bn[e] = (unsigned)((u >> sh) & 255);
          vl[e] = ok;
        }
        #pragma unroll
        for (int e = 0; e < 8; ++e) {
          if (vl[e]) {
            bool first = true;
            #pragma unroll
            for (int p = 0; p < 8; ++p)
              if (p < e && vl[p] && bn[p] == bn[e]) first = false;
            if (first) {
              unsigned c = 0;
              #pragma unroll
              for (int q = 0; q < 8; ++q)
                if (q >= e && vl[q] && bn[q] == bn[e]) ++c;
              atomicAdd(&hist[bn[e]], c);
            }
          }
        }
      }
      __syncthreads();
      unsigned* sp = sA; unsigned* dp = sB;
      sp[tid] = hist[tid];
      __syncthreads();
      #pragma unroll
      for (int off = 1; off < 256; off <<= 1) {
        dp[tid] = sp[tid] + ((tid + off < 256) ? sp[tid + off] : 0u);
        __syncthreads();
        unsigned* tpp = sp; sp = dp; dp = tpp;
      }
      unsigned inc = sp[tid];
      unsigned cumAbove = (tid == 255) ? 0u : sp[tid + 1];
      if ((int)cumAbove < remaining && (int)inc >= remaining) {
        s_bsel = (unsigned)tid;
        s_larger = cumAbove;
        s_cnt = inc - cumAbove;
      }
      __syncthreads();
      prefix |= ((u64)s_bsel << sh);
      remaining -= (int)s_larger;
      int cnt = (int)s_cnt;
      __syncthreads();
      if (cnt <= 128) { broke = 1; sh_final = sh; break; }
    }
    u64 thr;
    int remfin;
    if (broke) {
      unsigned cg = 0;
      #pragma unroll
      for (int e = 0; e < 8; ++e) {
        int jj = c0 + e;
        if (jj <= t && (((S[suX(jj)] ^ prefix) >> sh_final) == 0)) ++cg;
      }
      unsigned* sp = sA; unsigned* dp = sB;
      sp[tid] = cg;
      __syncthreads();
      #pragma unroll
      for (int off = 1; off < 256; off <<= 1) {
        dp[tid] = sp[tid] + ((tid >= off) ? sp[tid - off] : 0u);
        __syncthreads();
        unsigned* tpp = sp; sp = dp; dp = tpp;
      }
      const int C = (int)sp[255];
      int pos = (int)(sp[tid] - cg);
      #pragma unroll
      for (int e = 0; e < 8; ++e) {
        int jj = c0 + e;
        if (jj <= t && (((S[suX(jj)] ^ prefix) >> sh_final) == 0)) cand[pos++] = jj;
      }
      __syncthreads();
      if (tid < C) ckey[tid] = S[suX(cand[tid])];
      __syncthreads();
      if (tid < C) {
        u64 k = ckey[tid];
        int g = 0, eq = 0;
        for (int j = 0; j < C; ++j) {
          g += (ckey[j] > k) ? 1 : 0;
          eq += (ckey[j] == k) ? 1 : 0;
        }
        if (g < remaining && remaining <= g + eq) {
          s_thr = k;
          s_remfin = remaining - g;
        }
      }
      __syncthreads();
      thr = s_thr;
      remfin = s_remfin;
    } else {
      thr = prefix;
      remfin = remaining;
    }
    __syncthreads();
    unsigned cg = 0, ct_ = 0;
    #pragma unroll
    for (int e = 0; e < 8; ++e) {
      int jj = c0 + e;
      if (jj <= t) {
        u64 u = S[suX(jj)];
        cg += (u > thr) ? 1u : 0u;
        ct_ += (u == thr) ? 1u : 0u;
      }
    }
    const unsigned pack = cg | (ct_ << 16);
    {
      unsigned* sp = sA; unsigned* dp = sB;
      sp[tid] = pack;
      __syncthreads();
      #pragma unroll
      for (int off = 1; off < 256; off <<= 1) {
        dp[tid] = sp[tid] + ((tid >= off) ? sp[tid - off] : 0u);
        __syncthreads();
        unsigned* tpp = sp; sp = dp; dp = tpp;
      }
      const unsigned excl = sp[tid] - pack;
      const unsigned tot = sp[255];
      const unsigned Gtot = tot & 0xFFFFu;
      const u64 ut = S[suX(t)];
      const unsigned gt = (ut > thr) ? 1u : 0u;
      const unsigned tt = (ut == thr) ? 1u : 0u;
      const int GtotX = (int)(Gtot - gt);
      int gpos = (int)(excl & 0xFFFFu);
      int tpos = (int)(excl >> 16);
      #pragma unroll
      for (int e = 0; e < 8; ++e) {
        int jj = c0 + e;
        if (jj > t) break;
        u64 u = S[suX(jj)];
        if (u > thr) {
          if (jj != t) outp[1 + gpos] = jj;
          ++gpos;
        } else if (u == thr) {
          if (jj != t && tpos < remfin) outp[1 + GtotX + tpos] = jj;
          ++tpos;
        }
      }
      if (tid == 0) {
        outp[0] = t;
        const unsigned Ttot = tot >> 16;
        int tb = (int)(Ttot - tt);
        int emitT = tb < remfin ? tb : remfin;
        selcnt[r0 + lr] = 1 + GtotX + emitT;  // 64 or 65
      }
    }
    __syncthreads();
  }
}

// ------------------------------------------------------------- sparse attention (LDS-staged)
__global__ __launch_bounds__(256) void k_attn(const f16* __restrict__ qr,
                                              const f16* __restrict__ kr,
                                              const f16* __restrict__ vv,
                                              const int* __restrict__ selcnt,
                                              const int* __restrict__ selidx,
                                              f16* __restrict__ y)
{
  const int blk = blockIdx.x;  // row*4 + kvh
  const int row = blk >> 2, kvh = blk & 3;
  const int b = row >> 11;
  const int tid = threadIdx.x, lane = tid & 63, wave = tid >> 6;
  const int cnt = selcnt[row];
  __shared__ int sidx[68];
  __shared__ __align__(16) f16 Kl[65 * 128];  // swizzled
  __shared__ __align__(16) f16 Vl[65 * 128];  // linear
  __shared__ f16 qlds[4][128];
  __shared__ float pl[4][66];
  if (tid < cnt) sidx[tid] = selidx[(size_t)row * 68 + tid];
  *(f16x2*)&qlds[wave][lane * 2] =
      *(const f16x2*)&qr[((size_t)row * 16 + kvh * 4 + wave) * 128 + lane * 2];
  __syncthreads();  // sidx ready

  const int nch = cnt * 16;
  for (int c = tid; c < nch; c += 256) {
    const int r = c >> 4, ch = c & 15;
    const size_t kbase = ((size_t)(b * 2048 + sidx[r])) * 512 + kvh * 128 + ch * 8;
    f16x8 k8 = *(const f16x8*)&kr[kbase];
    *(f16x8*)&Kl[r * 128 + ((ch ^ (r & 15)) * 8)] = k8;
    f16x8 v8 = *(const f16x8*)&vv[kbase];
    *(f16x8*)&Vl[r * 128 + ch * 8] = v8;
  }
  __syncthreads();

  const float SCALE = 0.08838834764831845f;  // 1/sqrt(128)
  auto dotk = [&](int r) -> float {
    const int sw = r & 15;
    float s = 0.0f;
    #pragma unroll
    for (int i = 0; i < 16; ++i) {
      f16x8 k8 = *(const f16x8*)&Kl[r * 128 + ((i ^ sw) * 8)];
      f16x8 q8 = *(const f16x8*)&qlds[wave][i * 8];
      #pragma unroll
      for (int e = 0; e < 4; ++e) {
        f16x2 ka; ka.x = k8[2 * e]; ka.y = k8[2 * e + 1];
        f16x2 qa; qa.x = q8[2 * e]; qa.y = q8[2 * e + 1];
        s = __builtin_amdgcn_fdot2(ka, qa, s, false);
      }
    }
    return s * SCALE;
  };

  float s1 = -__builtin_inff(), s2 = -__builtin_inff();
  if (lane < cnt) s1 = dotk(lane);
  if (lane + 64 < cnt) s2 = dotk(lane + 64);  // only lane 0, cnt==65
  float mx = fmaxf(s1, s2);
  #pragma unroll
  for (int off = 32; off; off >>= 1) mx = fmaxf(mx, __shfl_xor(mx, off));
  float p1 = (lane < cnt) ? __expf(s1 - mx) : 0.0f;
  float p2 = (lane + 64 < cnt) ? __expf(s2 - mx) : 0.0f;
  float l = p1 + p2;
  #pragma unroll
  for (int off = 32; off; off >>= 1) l += __shfl_xor(l, off);
  float linv = 1.0f / l;
  pl[wave][lane] = p1;
  if (lane == 0) pl[wave][64] = p2;
  __syncthreads();

  float y0 = 0.0f, y1 = 0.0f;
  const int d2 = lane * 2;
  for (int j = 0; j < cnt; ++j) {
    float p = pl[wave][j];
    f16x2 v2 = *(const f16x2*)&Vl[j * 128 + d2];
    y0 = fmaf(p, (float)v2.x, y0);
    y1 = fmaf(p, (float)v2.y, y1);
  }
  y0 *= linv; y1 *= linv;
  f16x2 o; o.x = (f16)y0; o.y = (f16)y1;
  *(f16x2*)&y[(size_t)row * 2048 + (kvh * 4 + wave) * 128 + d2] = o;
}

// ================================================================ launch
extern "C" void kernel_launch(void* const* d_in, const int* in_sizes, int n_in,
                              void* d_out, int out_size, void* d_ws, size_t ws_size,
                              hipStream_t stream)
{
  (void)in_sizes; (void)n_in; (void)out_size; (void)ws_size;
  const float* x   = (const float*)d_in[0];
  const float* Wq  = (const float*)d_in[1];
  const float* bq  = (const float*)d_in[2];
  const float* Wkd = (const float*)d_in[3];
  const float* bkd = (const float*)d_in[4];
  const float* Wku = (const float*)d_in[5];
  const float* bku = (const float*)d_in[6];
  const float* Wo  = (const float*)d_in[7];
  const float* bo  = (const float*)d_in[8];
  float* out = (float*)d_out;

  char* ws = (char*)d_ws;
  size_t o = 0;
  auto alloc = [&](size_t bytes) -> void* {
    o = (o + 255) & ~(size_t)255;
    void* p = ws + o;
    o += bytes;
    return p;
  };
  f16* WqT   = (f16*)alloc(2048ull * 2048 * 2);
  f16* WoT   = (f16*)alloc(2048ull * 2048 * 2);
  f16* WkdT  = (f16*)alloc(512ull * 2048 * 2);
  f16* WkuT  = (f16*)alloc(1024ull * 512 * 2);
  f16* xh    = (f16*)alloc(4096ull * 2048 * 2);
  f16* qmain = (f16*)alloc(4096ull * 2048 * 2);  // reused as y after rope
  f16* kvh_  = (f16*)alloc(4096ull * 1024 * 2);
  f16* cbf   = (f16*)alloc(4096ull * 512 * 2);
  float* rc  = (float*)alloc(2048ull * 64 * 4);
  float* rs  = (float*)alloc(2048ull * 64 * 4);
  f16* qrope = (f16*)alloc(4096ull * 2048 * 2);
  f16* krope = (f16*)alloc(4096ull * 512 * 2);
  f16* vbf   = (f16*)alloc(4096ull * 512 * 2);
  int* selcnt = (int*)alloc(4096ull * 4);
  int* selidx = (int*)alloc(4096ull * 68 * 4);
  double* Bsel = (double*)alloc(2048ull * 128 * 8);
  double* bsel = (double*)alloc(128 * 8);
  double* qs64 = (double*)alloc(4096ull * 64 * 8);
  double* ks64 = (double*)alloc(4096ull * 64 * 8);
  double* ksT  = (double*)alloc(2ull * 64 * 2048 * 8);
  f16* yh = qmain;               // alias: qmain dead after k_rope_q
  double* partial = (double*)qrope;  // alias: 16 MiB, dead until k_rope_q writes qrope

  // --- weight prep ---
  k_transpose_cast<<<dim3(64, 64), 256, 0, stream>>>(Wq, WqT, 2048, 2048);
  k_transpose_cast<<<dim3(16, 64), 256, 0, stream>>>(Wkd, WkdT, 2048, 512);
  k_transpose_cast<<<dim3(32, 16), 256, 0, stream>>>(Wku, WkuT, 512, 1024);
  k_transpose_cast<<<dim3(64, 64), 256, 0, stream>>>(Wo, WoT, 2048, 2048);
  k_cast_f16<<<8192, 256, 0, stream>>>(x, xh, 2097152);

  // --- fp64 selector path (split-K: 4 slices -> fixed-order reduce) ---
  k_prep_sel<<<2048, 64, 0, stream>>>(Wq, Wkd, Wku, Bsel);
  k_bias_sel<<<1, 128, 0, stream>>>(bq, bkd, Wku, bku, bsel);
  k_gemm_sel_f64<<<dim3(128, 2, 4), 256, 0, stream>>>(x, Bsel, partial);
  k_sel_reduce<<<2048, 256, 0, stream>>>(partial, bsel, qs64, ks64);
  k_transpose64<<<dim3(2, 64, 2), 256, 0, stream>>>(ks64, ksT);

  // --- fp16 MFMA main path ---
  k_gemm_bt<true><<<dim3(32, 16), 256, 0, stream>>>(xh, WqT, bq, nullptr, qmain,
                                                    4096, 2048, 2048, 2048, 2048, 2048);
  k_gemm_bt<true><<<dim3(32, 4), 256, 0, stream>>>(xh, WkdT, bkd, nullptr, cbf,
                                                   4096, 512, 2048, 2048, 2048, 512);
  k_gemm_bt<true><<<dim3(32, 8), 256, 0, stream>>>(cbf, WkuT, bku, nullptr, kvh_,
                                                   4096, 1024, 512, 512, 512, 1024);

  // --- RoPE (k_rope_q overwrites qrope AFTER k_sel_reduce consumed the alias) ---
  k_rope_table<<<2048, 64, 0, stream>>>(rc, rs);
  k_rope_q<<<16384, 256, 0, stream>>>(qmain, rc, rs, qrope);
  k_rope_kv<<<4096, 256, 0, stream>>>(kvh_, rc, rs, krope, vbf);

  // --- selector top-k ---
  k_topk64<<<2048, 256, 0, stream>>>(qs64, ksT, selcnt, selidx);

  // --- sparse attention ---
  k_attn<<<16384, 256, 0, stream>>>(qrope, krope, vbf, selcnt, selidx, yh);

  // --- output projection ---
  k_gemm_bt<false><<<dim3(32, 16), 256, 0, stream>>>(yh, WoT, bo, out, nullptr,
                                                     4096, 2048, 2048, 2048, 2048, 2048);
}